// Round 1
// baseline (428.035 us; speedup 1.0000x reference)
//
#include <hip/hip_runtime.h>
#include <stdint.h>

// TriXTile: out = (relu((x @ sign(up_w)^T) * up_scale) @ sign(down_w)^T) * down_scale * out_scale
// Round 1: bf16-MFMA path. Prepass converts x->bf16 and weights->sign(bf16) in ws;
// two m97-structure 128x128 GEMMs (global_load_lds 16B staging, 16x16x32 bf16 MFMA).

#define M_TOK 4096
#define DM 2048
#define DH 8192

typedef __attribute__((ext_vector_type(8))) short bf16x8;
typedef __attribute__((ext_vector_type(4))) float f32x4;

__device__ __forceinline__ ushort f2bf_rne(float f) {
  union { float f; uint32_t u; } c; c.f = f;
  uint32_t u = c.u;
  uint32_t r = (u + 0x7FFFu + ((u >> 16) & 1u)) >> 16;
  return (ushort)r;
}

__device__ __forceinline__ ushort signbf(float f) {
  union { float f; uint32_t u; } c; c.f = f;
  uint32_t mag = c.u & 0x7FFFFFFFu;
  return mag ? (ushort)(0x3F80u | ((c.u >> 16) & 0x8000u)) : (ushort)0;
}

__device__ __forceinline__ void gload_lds16(const void* g, void* l) {
  __builtin_amdgcn_global_load_lds(
      (const __attribute__((address_space(1))) void*)g,
      (__attribute__((address_space(3))) void*)l, 16, 0, 0);
}

__global__ void cvt_bf16_kernel(const float* __restrict__ in,
                                ushort* __restrict__ out, int n4) {
  int stride = gridDim.x * blockDim.x;
  for (int i = blockIdx.x * blockDim.x + threadIdx.x; i < n4; i += stride) {
    float4 v = ((const float4*)in)[i];
    ushort4 o;
    o.x = f2bf_rne(v.x); o.y = f2bf_rne(v.y);
    o.z = f2bf_rne(v.z); o.w = f2bf_rne(v.w);
    ((ushort4*)out)[i] = o;
  }
}

__global__ void sign_bf16_kernel(const float* __restrict__ in,
                                 ushort* __restrict__ out, int n4) {
  int stride = gridDim.x * blockDim.x;
  for (int i = blockIdx.x * blockDim.x + threadIdx.x; i < n4; i += stride) {
    float4 v = ((const float4*)in)[i];
    ushort4 o;
    o.x = signbf(v.x); o.y = signbf(v.y);
    o.z = signbf(v.z); o.w = signbf(v.w);
    ((ushort4*)out)[i] = o;
  }
}

// C = A[M,K] @ B[N,K]^T, bf16 in, f32 acc.
// EPI==0: C bf16, val = relu(acc*scale[col])
// EPI==1: C f32,  val = acc*scale[col]*oscale[0]
template <int EPI>
__global__ __launch_bounds__(256) void gemm_bt_kernel(
    const ushort* __restrict__ A, const ushort* __restrict__ B,
    void* __restrict__ Cv, const float* __restrict__ scale,
    const float* __restrict__ oscale, int M, int N, int K) {
  constexpr int BM = 128, BN = 128, BK = 32;
  __shared__ __align__(16) ushort lA[BM * BK];  // 8 KB, row-major [128][32]
  __shared__ __align__(16) ushort lB[BN * BK];  // 8 KB

  const int nbn = N / BN;
  const int nwg = gridDim.x;
  const int bid = blockIdx.x;
  // XCD-aware bijective swizzle (grid % 8 == 0 for all our launches)
  const int cpx = nwg >> 3;
  const int swz = (bid & 7) * cpx + (bid >> 3);
  const int bm = swz / nbn, bn = swz % nbn;

  const int tid = threadIdx.x;
  const int lane = tid & 63;
  const int wv = tid >> 6;          // wave 0..3
  const int wm = wv >> 1, wn = wv & 1;  // 2x2 waves, 64x64 each
  const int lr = lane & 15, lg = lane >> 4;

  f32x4 acc[4][4] = {};

  // Staging: thread t supplies 16B destined for lds byte (p*4096 + t*16):
  // row = p*64 + t/4, k-elem offset = (t%4)*8
  const int arow = tid >> 2;
  const int ake = (tid & 3) * 8;
  const ushort* aS0 = A + (size_t)(bm * BM + arow) * K + ake;
  const ushort* aS1 = A + (size_t)(bm * BM + 64 + arow) * K + ake;
  const ushort* bS0 = B + (size_t)(bn * BN + arow) * K + ake;
  const ushort* bS1 = B + (size_t)(bn * BN + 64 + arow) * K + ake;

  // wave-uniform LDS dest bases (lane writes base + lane*16)
  char* lAc = (char*)lA + wv * 1024;
  char* lBc = (char*)lB + wv * 1024;

  for (int k0 = 0; k0 < K; k0 += BK) {
    gload_lds16(aS0 + k0, lAc);
    gload_lds16(aS1 + k0, lAc + 4096);
    gload_lds16(bS0 + k0, lBc);
    gload_lds16(bS1 + k0, lBc + 4096);
    __syncthreads();  // compiler drains vmcnt before barrier

    bf16x8 af[4], bfr[4];
#pragma unroll
    for (int i = 0; i < 4; ++i)
      af[i] = *(const bf16x8*)&lA[(wm * 64 + i * 16 + lr) * BK + lg * 8];
#pragma unroll
    for (int j = 0; j < 4; ++j)
      bfr[j] = *(const bf16x8*)&lB[(wn * 64 + j * 16 + lr) * BK + lg * 8];

#pragma unroll
    for (int i = 0; i < 4; ++i)
#pragma unroll
      for (int j = 0; j < 4; ++j)
        acc[i][j] = __builtin_amdgcn_mfma_f32_16x16x32_bf16(af[i], bfr[j],
                                                            acc[i][j], 0, 0, 0);
    __syncthreads();  // protect LDS before next stage
  }

  // Epilogue. C/D layout (m89-verified): col = lane&15, row = (lane>>4)*4 + reg
  if (EPI == 0) {
    ushort* C = (ushort*)Cv;
#pragma unroll
    for (int j = 0; j < 4; ++j) {
      int gcol = bn * BN + wn * 64 + j * 16 + lr;
      float sc = scale[gcol];
#pragma unroll
      for (int i = 0; i < 4; ++i) {
        int gr = bm * BM + wm * 64 + i * 16 + lg * 4;
#pragma unroll
        for (int r = 0; r < 4; ++r) {
          float v = acc[i][j][r] * sc;
          v = v > 0.f ? v : 0.f;
          C[(size_t)(gr + r) * N + gcol] = f2bf_rne(v);
        }
      }
    }
  } else {
    float* C = (float*)Cv;
    float osc = oscale[0];
#pragma unroll
    for (int j = 0; j < 4; ++j) {
      int gcol = bn * BN + wn * 64 + j * 16 + lr;
      float sc = scale[gcol] * osc;
#pragma unroll
      for (int i = 0; i < 4; ++i) {
        int gr = bm * BM + wm * 64 + i * 16 + lg * 4;
#pragma unroll
        for (int r = 0; r < 4; ++r) {
          C[(size_t)(gr + r) * N + gcol] = acc[i][j][r] * sc;
        }
      }
    }
  }
}

extern "C" void kernel_launch(void* const* d_in, const int* in_sizes, int n_in,
                              void* d_out, int out_size, void* d_ws,
                              size_t ws_size, hipStream_t stream) {
  const float* x   = (const float*)d_in[0];  // [2,2048,2048] -> [4096,2048]
  const float* upw = (const float*)d_in[1];  // [8192,2048]
  const float* dnw = (const float*)d_in[2];  // [2048,8192]
  const float* ups = (const float*)d_in[3];  // [8192]
  const float* dns = (const float*)d_in[4];  // [2048]
  const float* osc = (const float*)d_in[5];  // [1]
  float* out = (float*)d_out;                // [4096,2048] f32

  char* ws = (char*)d_ws;
  // ws layout: x_bf16 (16MB) | up_sign_bf16 (32MB) | dn_sign_bf16 (32MB) | hidden_bf16 (64MB)
  ushort* xb  = (ushort*)(ws);
  ushort* upb = (ushort*)(ws + 16777216);
  ushort* dnb = (ushort*)(ws + 16777216 + 33554432);
  ushort* hid = (ushort*)(ws + 16777216 + 33554432 + 33554432);

  cvt_bf16_kernel<<<2048, 256, 0, stream>>>(x, xb, (M_TOK * DM) / 4);
  sign_bf16_kernel<<<2048, 256, 0, stream>>>(upw, upb, (DH * DM) / 4);
  sign_bf16_kernel<<<2048, 256, 0, stream>>>(dnw, dnb, (DM * DH) / 4);

  // GEMM1: hidden[4096,8192] = xb @ upb^T, relu(*up_scale) -> bf16
  gemm_bt_kernel<0><<<(M_TOK / 128) * (DH / 128), 256, 0, stream>>>(
      xb, upb, (void*)hid, ups, nullptr, M_TOK, DH, DM);
  // GEMM2: out[4096,2048] = hid @ dnb^T, *down_scale*out_scale -> f32
  gemm_bt_kernel<1><<<(M_TOK / 128) * (DM / 128), 256, 0, stream>>>(
      hid, dnb, (void*)out, dns, osc, M_TOK, DM, DH);
}

// Round 2
// 307.252 us; speedup vs baseline: 1.3931x; 1.3931x over previous
//
#include <hip/hip_runtime.h>
#include <stdint.h>

// TriXTile: out = (relu((x @ sign(up_w)^T) * up_scale) @ sign(down_w)^T) * down_scale * out_scale
// Round 2: deep-pipelined bf16 GEMM. 256x128 tile, BK=64, 8 waves, 3-buffer LDS,
// counted vmcnt(6) (never 0 in main loop), raw s_barrier, T2 XOR-swizzle, setprio.

#define M_TOK 4096
#define DM 2048
#define DH 8192

typedef __attribute__((ext_vector_type(8))) short bf16x8;
typedef __attribute__((ext_vector_type(4))) float f32x4;

__device__ __forceinline__ ushort f2bf_rne(float f) {
  union { float f; uint32_t u; } c; c.f = f;
  uint32_t u = c.u;
  uint32_t r = (u + 0x7FFFu + ((u >> 16) & 1u)) >> 16;
  return (ushort)r;
}

__device__ __forceinline__ ushort signbf(float f) {
  union { float f; uint32_t u; } c; c.f = f;
  uint32_t mag = c.u & 0x7FFFFFFFu;
  return mag ? (ushort)(0x3F80u | ((c.u >> 16) & 0x8000u)) : (ushort)0;
}

#define GLD16(g, l)                                                     \
  __builtin_amdgcn_global_load_lds(                                     \
      (const __attribute__((address_space(1))) void*)(g),               \
      (__attribute__((address_space(3))) void*)(l), 16, 0, 0)

__global__ void cvt_bf16_kernel(const float* __restrict__ in,
                                ushort* __restrict__ out, int n4) {
  int stride = gridDim.x * blockDim.x;
  for (int i = blockIdx.x * blockDim.x + threadIdx.x; i < n4; i += stride) {
    float4 v = ((const float4*)in)[i];
    ushort4 o;
    o.x = f2bf_rne(v.x); o.y = f2bf_rne(v.y);
    o.z = f2bf_rne(v.z); o.w = f2bf_rne(v.w);
    ((ushort4*)out)[i] = o;
  }
}

__global__ void sign_bf16_kernel(const float* __restrict__ in,
                                 ushort* __restrict__ out, int n4) {
  int stride = gridDim.x * blockDim.x;
  for (int i = blockIdx.x * blockDim.x + threadIdx.x; i < n4; i += stride) {
    float4 v = ((const float4*)in)[i];
    ushort4 o;
    o.x = signbf(v.x); o.y = signbf(v.y);
    o.z = signbf(v.z); o.w = signbf(v.w);
    ((ushort4*)out)[i] = o;
  }
}

// C = A[M,K] @ B[N,K]^T, bf16 in, f32 acc.
// EPI==0: C bf16, val = relu(acc*scale[col])
// EPI==1: C f32,  val = acc*scale[col]*oscale[0]
// BM=256, BN=128, BK=64. 512 threads = 8 waves (4 M x 2 N), 64x64 per wave.
// LDS: 3 buffers x (A 32KB + B 16KB) = 144KB (dynamic).
// Pipeline: distance-2 K-tile prefetch via global_load_lds, vmcnt(6) per iter.
// LDS swizzle: physical (row, cB) holds global (row, cB ^ ((row&7)<<4));
// staging pre-swizzles the GLOBAL source (linear LDS dest), reads apply the XOR.
template <int EPI>
__global__ __launch_bounds__(512, 2) void gemm_bt_kernel(
    const ushort* __restrict__ A, const ushort* __restrict__ B,
    void* __restrict__ Cv, const float* __restrict__ scale,
    const float* __restrict__ oscale, int M, int N, int K) {
  constexpr int BM = 256, BN = 128, BK = 64;
  constexpr int ABYTES = BM * BK * 2;      // 32768
  constexpr int BBYTES = BN * BK * 2;      // 16384
  constexpr int BUFB = ABYTES + BBYTES;    // 49152
  extern __shared__ char smem[];

  const int nbn = N / BN;
  const int nwg = gridDim.x;
  const int bid = blockIdx.x;
  // XCD-aware bijective swizzle (grids are 1024 / 256, both % 8 == 0)
  const int cpx = nwg >> 3;
  const int swz = (bid & 7) * cpx + (bid >> 3);
  const int bm = swz / nbn, bn = swz % nbn;

  const int tid = threadIdx.x;
  const int lane = tid & 63;
  const int wv = tid >> 6;              // 0..7
  const int wm = wv >> 1, wn = wv & 1;  // 4x2 wave grid
  const int lr = lane & 15, lg = lane >> 4;

  // Staging source addressing. Thread t covers LDS physical bytes
  // [issue*8192 + t*16, +16). row = issue*64 + t/8, physColByte = (t%8)*16.
  // Source column pre-swizzled: srcColByte = physColByte ^ ((row&7)<<4).
  const int srow = tid >> 3;                        // 0..63
  const int scol = ((tid & 7) ^ (srow & 7)) << 3;   // element offset
  const ushort* aS = A + (size_t)(bm * BM + srow) * K + scol;
  const ushort* bS = B + (size_t)(bn * BN + srow) * K + scol;
  const int ldsl = wv * 1024;  // wave-uniform lane-block base

  f32x4 acc[4][4] = {};
  const int nt = K / BK;

  auto STAGE = [&](int t, int q) {
    char* dA = smem + q * BUFB;
    char* dB = dA + ABYTES;
    const ushort* a0 = aS + (size_t)t * BK;
    const ushort* b0 = bS + (size_t)t * BK;
#pragma unroll
    for (int a = 0; a < 4; ++a)
      GLD16(a0 + (size_t)(a * 64) * K, dA + a * 8192 + ldsl);
#pragma unroll
    for (int b = 0; b < 2; ++b)
      GLD16(b0 + (size_t)(b * 64) * K, dB + b * 8192 + ldsl);
  };

  // Prologue: tiles 0,1 in flight (12 loads); wait tile 0 (leave 6).
  STAGE(0, 0);
  STAGE(1, 1);
  asm volatile("s_waitcnt vmcnt(6)" ::: "memory");
  __builtin_amdgcn_s_barrier();

  const int xorv = (lr & 7) << 4;
  int cur = 0;
  for (int t = 0; t < nt; ++t) {
    int nx = cur + 2; nx = (nx >= 3) ? nx - 3 : nx;
    if (t + 2 < nt) STAGE(t + 2, nx);

    const char* cA = smem + cur * BUFB;
    const char* cB = cA + ABYTES;
    bf16x8 af[2][4], bfr[2][4];
#pragma unroll
    for (int ks = 0; ks < 2; ++ks) {
      int ko = ((ks << 6) + (lg << 4)) ^ xorv;
#pragma unroll
      for (int i = 0; i < 4; ++i)
        af[ks][i] = *(const bf16x8*)(cA + ((wm * 64 + i * 16 + lr) << 7) + ko);
#pragma unroll
      for (int j = 0; j < 4; ++j)
        bfr[ks][j] = *(const bf16x8*)(cB + ((wn * 64 + j * 16 + lr) << 7) + ko);
    }

    __builtin_amdgcn_s_setprio(1);
#pragma unroll
    for (int ks = 0; ks < 2; ++ks)
#pragma unroll
      for (int i = 0; i < 4; ++i)
#pragma unroll
        for (int j = 0; j < 4; ++j)
          acc[i][j] = __builtin_amdgcn_mfma_f32_16x16x32_bf16(
              af[ks][i], bfr[ks][j], acc[i][j], 0, 0, 0);
    __builtin_amdgcn_s_setprio(0);

    // End-of-iter: tile t+1 must be landed for next iter's reads.
    if (t + 2 < nt) {
      asm volatile("s_waitcnt vmcnt(6)" ::: "memory");  // leaves tile t+2 in flight
    } else if (t + 1 < nt) {
      asm volatile("s_waitcnt vmcnt(0)" ::: "memory");  // tail drain
    }
    __builtin_amdgcn_s_barrier();
    cur = cur + 1; if (cur == 3) cur = 0;
  }

  // Epilogue. C/D layout (m89-verified): col = lane&15, row = (lane>>4)*4 + reg
  if (EPI == 0) {
    ushort* C = (ushort*)Cv;
#pragma unroll
    for (int j = 0; j < 4; ++j) {
      int gcol = bn * BN + wn * 64 + j * 16 + lr;
      float sc = scale[gcol];
#pragma unroll
      for (int i = 0; i < 4; ++i) {
        int gr = bm * BM + wm * 64 + i * 16 + lg * 4;
#pragma unroll
        for (int r = 0; r < 4; ++r) {
          float v = acc[i][j][r] * sc;
          v = v > 0.f ? v : 0.f;
          C[(size_t)(gr + r) * N + gcol] = f2bf_rne(v);
        }
      }
    }
  } else {
    float* C = (float*)Cv;
    float osc = oscale[0];
#pragma unroll
    for (int j = 0; j < 4; ++j) {
      int gcol = bn * BN + wn * 64 + j * 16 + lr;
      float sc = scale[gcol] * osc;
#pragma unroll
      for (int i = 0; i < 4; ++i) {
        int gr = bm * BM + wm * 64 + i * 16 + lg * 4;
#pragma unroll
        for (int r = 0; r < 4; ++r) {
          C[(size_t)(gr + r) * N + gcol] = acc[i][j][r] * sc;
        }
      }
    }
  }
}

extern "C" void kernel_launch(void* const* d_in, const int* in_sizes, int n_in,
                              void* d_out, int out_size, void* d_ws,
                              size_t ws_size, hipStream_t stream) {
  const float* x   = (const float*)d_in[0];  // [2,2048,2048] -> [4096,2048]
  const float* upw = (const float*)d_in[1];  // [8192,2048]
  const float* dnw = (const float*)d_in[2];  // [2048,8192]
  const float* ups = (const float*)d_in[3];  // [8192]
  const float* dns = (const float*)d_in[4];  // [2048]
  const float* osc = (const float*)d_in[5];  // [1]
  float* out = (float*)d_out;                // [4096,2048] f32

  char* ws = (char*)d_ws;
  ushort* xb  = (ushort*)(ws);
  ushort* upb = (ushort*)(ws + 16777216);
  ushort* dnb = (ushort*)(ws + 16777216 + 33554432);
  ushort* hid = (ushort*)(ws + 16777216 + 33554432 + 33554432);

  cvt_bf16_kernel<<<2048, 256, 0, stream>>>(x, xb, (M_TOK * DM) / 4);
  sign_bf16_kernel<<<2048, 256, 0, stream>>>(upw, upb, (DH * DM) / 4);
  sign_bf16_kernel<<<2048, 256, 0, stream>>>(dnw, dnb, (DM * DH) / 4);

  const int smem_bytes = 3 * (256 * 64 * 2 + 128 * 64 * 2);  // 147456
  (void)hipFuncSetAttribute(reinterpret_cast<const void*>(gemm_bt_kernel<0>),
                            hipFuncAttributeMaxDynamicSharedMemorySize,
                            smem_bytes);
  (void)hipFuncSetAttribute(reinterpret_cast<const void*>(gemm_bt_kernel<1>),
                            hipFuncAttributeMaxDynamicSharedMemorySize,
                            smem_bytes);

  // GEMM1: hidden[4096,8192] = xb @ upb^T, relu(*up_scale) -> bf16
  gemm_bt_kernel<0><<<(M_TOK / 256) * (DH / 128), 512, smem_bytes, stream>>>(
      xb, upb, (void*)hid, ups, nullptr, M_TOK, DH, DM);
  // GEMM2: out[4096,2048] = hid @ dnb^T, *down_scale*out_scale -> f32
  gemm_bt_kernel<1><<<(M_TOK / 256) * (DM / 128), 512, smem_bytes, stream>>>(
      hid, dnb, (void*)out, dns, osc, M_TOK, DM, DH);
}

// Round 3
// 305.123 us; speedup vs baseline: 1.4028x; 1.0070x over previous
//
#include <hip/hip_runtime.h>
#include <stdint.h>

// TriXTile: out = (relu((x @ sign(up_w)^T) * up_scale) @ sign(down_w)^T) * down_scale * out_scale
// Round 3: GEMM1 -> 256x256 tile, 8 waves (2Mx4N, 128x64 per wave), BK=64,
// 4-phase schedule, counted vmcnt(4), provably race-free stage placement,
// T2 XOR swizzle, setprio. GEMM2 keeps round-2 structure (grid constraint).

#define M_TOK 4096
#define DM 2048
#define DH 8192

typedef __attribute__((ext_vector_type(8))) short bf16x8;
typedef __attribute__((ext_vector_type(4))) float f32x4;

__device__ __forceinline__ ushort f2bf_rne(float f) {
  union { float f; uint32_t u; } c; c.f = f;
  uint32_t u = c.u;
  uint32_t r = (u + 0x7FFFu + ((u >> 16) & 1u)) >> 16;
  return (ushort)r;
}

__device__ __forceinline__ ushort signbf(float f) {
  union { float f; uint32_t u; } c; c.f = f;
  uint32_t mag = c.u & 0x7FFFFFFFu;
  return mag ? (ushort)(0x3F80u | ((c.u >> 16) & 0x8000u)) : (ushort)0;
}

#define GLD16(g, l)                                                     \
  __builtin_amdgcn_global_load_lds(                                     \
      (const __attribute__((address_space(1))) void*)(g),               \
      (__attribute__((address_space(3))) void*)(l), 16, 0, 0)

__global__ void cvt_bf16_kernel(const float* __restrict__ in,
                                ushort* __restrict__ out, int n4) {
  int stride = gridDim.x * blockDim.x;
  for (int i = blockIdx.x * blockDim.x + threadIdx.x; i < n4; i += stride) {
    float4 v = ((const float4*)in)[i];
    ushort4 o;
    o.x = f2bf_rne(v.x); o.y = f2bf_rne(v.y);
    o.z = f2bf_rne(v.z); o.w = f2bf_rne(v.w);
    ((ushort4*)out)[i] = o;
  }
}

__global__ void sign_bf16_kernel(const float* __restrict__ in,
                                 ushort* __restrict__ out, int n4) {
  int stride = gridDim.x * blockDim.x;
  for (int i = blockIdx.x * blockDim.x + threadIdx.x; i < n4; i += stride) {
    float4 v = ((const float4*)in)[i];
    ushort4 o;
    o.x = signbf(v.x); o.y = signbf(v.y);
    o.z = signbf(v.z); o.w = signbf(v.w);
    ((ushort4*)out)[i] = o;
  }
}

// ---------------- 256x256 4-phase kernel (GEMM1) ----------------
// C = A[M,K] @ B[N,K]^T. 512 thr, 8 waves 2Mx4N, wave tile 128x64, BK=64.
// LDS: 2 buffers x (A 32KB + B 32KB) = 128KB. Stage unit = 8KB = 64 rows
// (one gload_lds per thread). Units: 0-3 = A rows u*64; 4-7 = B rows (u-4)*64.
// Phase p consumption: p0 = ks0 x Arows(frag0-3) x all B(ks0);
// p1 = ks1 x Arows(0-3) x B(ks1); p2 = ks0 x Arows(4-7); p3 = ks1 x Arows(4-7).
// => A units 0,2 and B units 4-7 are DEAD after p1; A units 1,3 after p3.
// Stage schedule (tile t): p0: (t+1)u6,u7  [opposite buffer, safe]
//                          p1: (t+1)u1,u3  [opposite buffer, safe]
//                          p2: (t+2)u0,u2  [read buffer; dead after p1 + full
//                                           bar/lgkm0/bar separation => safe]
//                          p3: (t+2)u4,u5  [read buffer; dead after p1 => safe]
// End of tile: vmcnt(4) retires all 8 units of tile t+1, leaves 4 of t+2.
template <int EPI>
__global__ __launch_bounds__(512, 2) void gemm256_bt_kernel(
    const ushort* __restrict__ A, const ushort* __restrict__ B,
    void* __restrict__ Cv, const float* __restrict__ scale,
    const float* __restrict__ oscale, int M, int N, int K) {
  constexpr int BK = 64;
  constexpr int TILEB = 256 * BK * 2;   // 32768 bytes per matrix tile
  constexpr int BUFB = 2 * TILEB;       // 65536 per buffer
  extern __shared__ char smem[];

  const int nbn = N >> 8;
  const int bid = blockIdx.x;
  const int cpx = gridDim.x >> 3;       // grid % 8 == 0 for our launches
  const int swz = (bid & 7) * cpx + (bid >> 3);
  const int bm = swz / nbn, bn = swz % nbn;

  const int tid = threadIdx.x;
  const int lane = tid & 63;
  const int wv = tid >> 6;
  const int wm = wv >> 2, wn = wv & 3;  // 2 x 4 wave grid
  const int lr = lane & 15, lg = lane >> 4;

  // Staging source addressing (pre-swizzled global column, linear LDS dest).
  const int srow = tid >> 3;                        // 0..63 within unit
  const int scol = ((tid & 7) ^ (srow & 7)) << 3;   // element offset
  const ushort* aS = A + (size_t)(bm * 256 + srow) * K + scol;
  const ushort* bS = B + (size_t)(bn * 256 + srow) * K + scol;
  const int ldsl = wv * 1024;

  auto STAGE = [&](int t, int u) {
    char* dst = smem + (t & 1) * BUFB + u * 8192 + ldsl;
    const ushort* src = (u < 4) ? aS + (size_t)(u * 64) * K + (size_t)t * BK
                                : bS + (size_t)((u - 4) * 64) * K + (size_t)t * BK;
    GLD16(src, dst);
  };

  const int nt = K >> 6;
  f32x4 acc[8][4] = {};

  // Prologue: tile0 full (8 units) + tile1 units 0,2,4,5; wait tile0.
#pragma unroll
  for (int u = 0; u < 8; ++u) STAGE(0, u);
  if (nt > 1) {
    STAGE(1, 0); STAGE(1, 2); STAGE(1, 4); STAGE(1, 5);
    asm volatile("s_waitcnt vmcnt(4)" ::: "memory");
  } else {
    asm volatile("s_waitcnt vmcnt(0)" ::: "memory");
  }
  __builtin_amdgcn_s_barrier();

  const int xorv = (lr & 7) << 4;
  const int k0 = (lg << 4) ^ xorv;          // ks0 byte offset within row
  const int k1 = (64 + (lg << 4)) ^ xorv;   // ks1
  const int abase = (wm * 128 + lr) * 128;
  const int bbase = TILEB + (wn * 64 + lr) * 128;

  for (int t = 0; t < nt; ++t) {
    const char* bufc = smem + (t & 1) * BUFB;
    const char* bA = bufc + abase;
    const char* bB = bufc + bbase;
    bf16x8 a[4], b0[4], b1[4];

    // ---- phase 0: ks0, A frags 0-3, all B ks0 ----
#pragma unroll
    for (int fr = 0; fr < 4; ++fr) a[fr] = *(const bf16x8*)(bA + fr * 2048 + k0);
#pragma unroll
    for (int fc = 0; fc < 4; ++fc) b0[fc] = *(const bf16x8*)(bB + fc * 2048 + k0);
    if (t + 1 < nt) { STAGE(t + 1, 6); STAGE(t + 1, 7); }
    __builtin_amdgcn_s_barrier();
    asm volatile("s_waitcnt lgkmcnt(0)" ::: "memory");
    __builtin_amdgcn_sched_barrier(0);
    __builtin_amdgcn_s_setprio(1);
#pragma unroll
    for (int fr = 0; fr < 4; ++fr)
#pragma unroll
      for (int fc = 0; fc < 4; ++fc)
        acc[fr][fc] = __builtin_amdgcn_mfma_f32_16x16x32_bf16(a[fr], b0[fc],
                                                              acc[fr][fc], 0, 0, 0);
    __builtin_amdgcn_s_setprio(0);
    __builtin_amdgcn_s_barrier();

    // ---- phase 1: ks1, A frags 0-3, all B ks1 ----
#pragma unroll
    for (int fr = 0; fr < 4; ++fr) a[fr] = *(const bf16x8*)(bA + fr * 2048 + k1);
#pragma unroll
    for (int fc = 0; fc < 4; ++fc) b1[fc] = *(const bf16x8*)(bB + fc * 2048 + k1);
    if (t + 1 < nt) { STAGE(t + 1, 1); STAGE(t + 1, 3); }
    __builtin_amdgcn_s_barrier();
    asm volatile("s_waitcnt lgkmcnt(0)" ::: "memory");
    __builtin_amdgcn_sched_barrier(0);
    __builtin_amdgcn_s_setprio(1);
#pragma unroll
    for (int fr = 0; fr < 4; ++fr)
#pragma unroll
      for (int fc = 0; fc < 4; ++fc)
        acc[fr][fc] = __builtin_amdgcn_mfma_f32_16x16x32_bf16(a[fr], b1[fc],
                                                              acc[fr][fc], 0, 0, 0);
    __builtin_amdgcn_s_setprio(0);
    __builtin_amdgcn_s_barrier();

    // ---- phase 2: ks0, A frags 4-7 (reuse b0) ----
#pragma unroll
    for (int fr = 0; fr < 4; ++fr)
      a[fr] = *(const bf16x8*)(bA + (fr + 4) * 2048 + k0);
    asm volatile("" ::: "memory");  // keep stages below the phase-1 barrier
    if (t + 2 < nt) { STAGE(t + 2, 0); STAGE(t + 2, 2); }
    __builtin_amdgcn_s_barrier();
    asm volatile("s_waitcnt lgkmcnt(0)" ::: "memory");
    __builtin_amdgcn_sched_barrier(0);
    __builtin_amdgcn_s_setprio(1);
#pragma unroll
    for (int fr = 0; fr < 4; ++fr)
#pragma unroll
      for (int fc = 0; fc < 4; ++fc)
        acc[fr + 4][fc] = __builtin_amdgcn_mfma_f32_16x16x32_bf16(
            a[fr], b0[fc], acc[fr + 4][fc], 0, 0, 0);
    __builtin_amdgcn_s_setprio(0);
    __builtin_amdgcn_s_barrier();

    // ---- phase 3: ks1, A frags 4-7 (reuse b1) ----
#pragma unroll
    for (int fr = 0; fr < 4; ++fr)
      a[fr] = *(const bf16x8*)(bA + (fr + 4) * 2048 + k1);
    asm volatile("" ::: "memory");
    if (t + 2 < nt) { STAGE(t + 2, 4); STAGE(t + 2, 5); }
    __builtin_amdgcn_s_barrier();
    asm volatile("s_waitcnt lgkmcnt(0)" ::: "memory");
    __builtin_amdgcn_sched_barrier(0);
    __builtin_amdgcn_s_setprio(1);
#pragma unroll
    for (int fr = 0; fr < 4; ++fr)
#pragma unroll
      for (int fc = 0; fc < 4; ++fc)
        acc[fr + 4][fc] = __builtin_amdgcn_mfma_f32_16x16x32_bf16(
            a[fr], b1[fc], acc[fr + 4][fc], 0, 0, 0);
    __builtin_amdgcn_s_setprio(0);
    // End-of-tile wait: retire all of tile t+1, leave t+2's 4 units in flight.
    if (t + 2 < nt) {
      asm volatile("s_waitcnt vmcnt(4)" ::: "memory");
    } else if (t + 1 < nt) {
      asm volatile("s_waitcnt vmcnt(0)" ::: "memory");
    }
    __builtin_amdgcn_s_barrier();
  }

  // Epilogue. C/D layout: col = lane&15, row = (lane>>4)*4 + reg.
  if (EPI == 0) {
    ushort* C = (ushort*)Cv;
#pragma unroll
    for (int fc = 0; fc < 4; ++fc) {
      int gcol = bn * 256 + wn * 64 + fc * 16 + lr;
      float sc = scale[gcol];
#pragma unroll
      for (int fr = 0; fr < 8; ++fr) {
        int gr = bm * 256 + wm * 128 + fr * 16 + lg * 4;
#pragma unroll
        for (int r = 0; r < 4; ++r) {
          float v = acc[fr][fc][r] * sc;
          v = v > 0.f ? v : 0.f;
          C[(size_t)(gr + r) * N + gcol] = f2bf_rne(v);
        }
      }
    }
  } else {
    float* C = (float*)Cv;
    float osc = oscale[0];
#pragma unroll
    for (int fc = 0; fc < 4; ++fc) {
      int gcol = bn * 256 + wn * 64 + fc * 16 + lr;
      float sc = scale[gcol] * osc;
#pragma unroll
      for (int fr = 0; fr < 8; ++fr) {
        int gr = bm * 256 + wm * 128 + fr * 16 + lg * 4;
#pragma unroll
        for (int r = 0; r < 4; ++r) {
          C[(size_t)(gr + r) * N + gcol] = acc[fr][fc][r] * sc;
        }
      }
    }
  }
}

// ---------------- round-2 256x128 kernel (GEMM2) ----------------
template <int EPI>
__global__ __launch_bounds__(512, 2) void gemm_bt_kernel(
    const ushort* __restrict__ A, const ushort* __restrict__ B,
    void* __restrict__ Cv, const float* __restrict__ scale,
    const float* __restrict__ oscale, int M, int N, int K) {
  constexpr int BM = 256, BN = 128, BK = 64;
  constexpr int ABYTES = BM * BK * 2;
  constexpr int BBYTES = BN * BK * 2;
  constexpr int BUFB = ABYTES + BBYTES;
  extern __shared__ char smem[];

  const int nbn = N / BN;
  const int nwg = gridDim.x;
  const int bid = blockIdx.x;
  const int cpx = nwg >> 3;
  const int swz = (bid & 7) * cpx + (bid >> 3);
  const int bm = swz / nbn, bn = swz % nbn;

  const int tid = threadIdx.x;
  const int lane = tid & 63;
  const int wv = tid >> 6;
  const int wm = wv >> 1, wn = wv & 1;
  const int lr = lane & 15, lg = lane >> 4;

  const int srow = tid >> 3;
  const int scol = ((tid & 7) ^ (srow & 7)) << 3;
  const ushort* aS = A + (size_t)(bm * BM + srow) * K + scol;
  const ushort* bS = B + (size_t)(bn * BN + srow) * K + scol;
  const int ldsl = wv * 1024;

  f32x4 acc[4][4] = {};
  const int nt = K / BK;

  auto STAGE = [&](int t, int q) {
    char* dA = smem + q * BUFB;
    char* dB = dA + ABYTES;
    const ushort* a0 = aS + (size_t)t * BK;
    const ushort* b0 = bS + (size_t)t * BK;
#pragma unroll
    for (int a = 0; a < 4; ++a)
      GLD16(a0 + (size_t)(a * 64) * K, dA + a * 8192 + ldsl);
#pragma unroll
    for (int b = 0; b < 2; ++b)
      GLD16(b0 + (size_t)(b * 64) * K, dB + b * 8192 + ldsl);
  };

  STAGE(0, 0);
  STAGE(1, 1);
  asm volatile("s_waitcnt vmcnt(6)" ::: "memory");
  __builtin_amdgcn_s_barrier();

  const int xorv = (lr & 7) << 4;
  int cur = 0;
  for (int t = 0; t < nt; ++t) {
    int nx = cur + 2; nx = (nx >= 3) ? nx - 3 : nx;
    if (t + 2 < nt) STAGE(t + 2, nx);

    const char* cA = smem + cur * BUFB;
    const char* cB = cA + ABYTES;
    bf16x8 af[2][4], bfr[2][4];
#pragma unroll
    for (int ks = 0; ks < 2; ++ks) {
      int ko = ((ks << 6) + (lg << 4)) ^ xorv;
#pragma unroll
      for (int i = 0; i < 4; ++i)
        af[ks][i] = *(const bf16x8*)(cA + ((wm * 64 + i * 16 + lr) << 7) + ko);
#pragma unroll
      for (int j = 0; j < 4; ++j)
        bfr[ks][j] = *(const bf16x8*)(cB + ((wn * 64 + j * 16 + lr) << 7) + ko);
    }

    __builtin_amdgcn_s_setprio(1);
#pragma unroll
    for (int ks = 0; ks < 2; ++ks)
#pragma unroll
      for (int i = 0; i < 4; ++i)
#pragma unroll
        for (int j = 0; j < 4; ++j)
          acc[i][j] = __builtin_amdgcn_mfma_f32_16x16x32_bf16(
              af[ks][i], bfr[ks][j], acc[i][j], 0, 0, 0);
    __builtin_amdgcn_s_setprio(0);

    if (t + 2 < nt) {
      asm volatile("s_waitcnt vmcnt(6)" ::: "memory");
    } else if (t + 1 < nt) {
      asm volatile("s_waitcnt vmcnt(0)" ::: "memory");
    }
    __builtin_amdgcn_s_barrier();
    cur = cur + 1; if (cur == 3) cur = 0;
  }

  if (EPI == 0) {
    ushort* C = (ushort*)Cv;
#pragma unroll
    for (int j = 0; j < 4; ++j) {
      int gcol = bn * BN + wn * 64 + j * 16 + lr;
      float sc = scale[gcol];
#pragma unroll
      for (int i = 0; i < 4; ++i) {
        int gr = bm * BM + wm * 64 + i * 16 + lg * 4;
#pragma unroll
        for (int r = 0; r < 4; ++r) {
          float v = acc[i][j][r] * sc;
          v = v > 0.f ? v : 0.f;
          C[(size_t)(gr + r) * N + gcol] = f2bf_rne(v);
        }
      }
    }
  } else {
    float* C = (float*)Cv;
    float osc = oscale[0];
#pragma unroll
    for (int j = 0; j < 4; ++j) {
      int gcol = bn * BN + wn * 64 + j * 16 + lr;
      float sc = scale[gcol] * osc;
#pragma unroll
      for (int i = 0; i < 4; ++i) {
        int gr = bm * BM + wm * 64 + i * 16 + lg * 4;
#pragma unroll
        for (int r = 0; r < 4; ++r) {
          C[(size_t)(gr + r) * N + gcol] = acc[i][j][r] * sc;
        }
      }
    }
  }
}

extern "C" void kernel_launch(void* const* d_in, const int* in_sizes, int n_in,
                              void* d_out, int out_size, void* d_ws,
                              size_t ws_size, hipStream_t stream) {
  const float* x   = (const float*)d_in[0];
  const float* upw = (const float*)d_in[1];
  const float* dnw = (const float*)d_in[2];
  const float* ups = (const float*)d_in[3];
  const float* dns = (const float*)d_in[4];
  const float* osc = (const float*)d_in[5];
  float* out = (float*)d_out;

  char* ws = (char*)d_ws;
  ushort* xb  = (ushort*)(ws);
  ushort* upb = (ushort*)(ws + 16777216);
  ushort* dnb = (ushort*)(ws + 16777216 + 33554432);
  ushort* hid = (ushort*)(ws + 16777216 + 33554432 + 33554432);

  cvt_bf16_kernel<<<2048, 256, 0, stream>>>(x, xb, (M_TOK * DM) / 4);
  sign_bf16_kernel<<<2048, 256, 0, stream>>>(upw, upb, (DH * DM) / 4);
  sign_bf16_kernel<<<2048, 256, 0, stream>>>(dnw, dnb, (DM * DH) / 4);

  const int smem1 = 2 * (256 * 64 * 2) * 2;                  // 131072
  const int smem2 = 3 * (256 * 64 * 2 + 128 * 64 * 2);       // 147456
  (void)hipFuncSetAttribute(reinterpret_cast<const void*>(gemm256_bt_kernel<0>),
                            hipFuncAttributeMaxDynamicSharedMemorySize, smem1);
  (void)hipFuncSetAttribute(reinterpret_cast<const void*>(gemm_bt_kernel<1>),
                            hipFuncAttributeMaxDynamicSharedMemorySize, smem2);

  // GEMM1: hidden[4096,8192] = xb @ upb^T, relu(*up_scale) -> bf16 (grid 512)
  gemm256_bt_kernel<0><<<(M_TOK / 256) * (DH / 256), 512, smem1, stream>>>(
      xb, upb, (void*)hid, ups, nullptr, M_TOK, DH, DM);
  // GEMM2: out[4096,2048] = hid @ dnb^T, *down_scale*out_scale -> f32 (grid 256)
  gemm_bt_kernel<1><<<(M_TOK / 256) * (DM / 128), 512, smem2, stream>>>(
      hid, dnb, (void*)out, dns, osc, M_TOK, DM, DH);
}

// Round 4
// 299.605 us; speedup vs baseline: 1.4287x; 1.0184x over previous
//
#include <hip/hip_runtime.h>
#include <stdint.h>

// TriXTile: out = (relu((x @ sign(up_w)^T) * up_scale) @ sign(down_w)^T) * down_scale * out_scale
// Round 4: GEMM1 phases reorganized by C-QUADRANT (disjoint accumulators per
// phase) so the matrix pipe drains phase q's MFMAs while waves issue phase
// q+1's ds_reads past the barrier. B frags register-resident across the tile.
// Staging/vmcnt schedule identical to round 3. GEMM2/prepass unchanged.

#define M_TOK 4096
#define DM 2048
#define DH 8192

typedef __attribute__((ext_vector_type(8))) short bf16x8;
typedef __attribute__((ext_vector_type(4))) float f32x4;

__device__ __forceinline__ ushort f2bf_rne(float f) {
  union { float f; uint32_t u; } c; c.f = f;
  uint32_t u = c.u;
  uint32_t r = (u + 0x7FFFu + ((u >> 16) & 1u)) >> 16;
  return (ushort)r;
}

__device__ __forceinline__ ushort signbf(float f) {
  union { float f; uint32_t u; } c; c.f = f;
  uint32_t mag = c.u & 0x7FFFFFFFu;
  return mag ? (ushort)(0x3F80u | ((c.u >> 16) & 0x8000u)) : (ushort)0;
}

#define GLD16(g, l)                                                     \
  __builtin_amdgcn_global_load_lds(                                     \
      (const __attribute__((address_space(1))) void*)(g),               \
      (__attribute__((address_space(3))) void*)(l), 16, 0, 0)

__global__ void cvt_bf16_kernel(const float* __restrict__ in,
                                ushort* __restrict__ out, int n4) {
  int stride = gridDim.x * blockDim.x;
  for (int i = blockIdx.x * blockDim.x + threadIdx.x; i < n4; i += stride) {
    float4 v = ((const float4*)in)[i];
    ushort4 o;
    o.x = f2bf_rne(v.x); o.y = f2bf_rne(v.y);
    o.z = f2bf_rne(v.z); o.w = f2bf_rne(v.w);
    ((ushort4*)out)[i] = o;
  }
}

__global__ void sign_bf16_kernel(const float* __restrict__ in,
                                 ushort* __restrict__ out, int n4) {
  int stride = gridDim.x * blockDim.x;
  for (int i = blockIdx.x * blockDim.x + threadIdx.x; i < n4; i += stride) {
    float4 v = ((const float4*)in)[i];
    ushort4 o;
    o.x = signbf(v.x); o.y = signbf(v.y);
    o.z = signbf(v.z); o.w = signbf(v.w);
    ((ushort4*)out)[i] = o;
  }
}

// ---------------- 256x256 quadrant-phase kernel (GEMM1) ----------------
// C = A[M,K] @ B[N,K]^T. 512 thr, 8 waves 2Mx4N, wave tile 128x64, BK=64.
// Phase q (q=0..3): ds-read A frags {2q,2q+1} (x2 ks); p0 also reads all B
// (8 reads, reused in registers). MFMA cluster q touches acc[2q..2q+1][*]
// ONLY -> no acc dependency between adjacent phases -> matrix pipe drains
// phase q while waves issue phase q+1 reads. Stage placement (same proof as
// r3): p0:(t+1)u6,u7  p1:(t+1)u1,u3  p2:(t+2)u0,u2  p3:(t+2)u4,u5; units
// 0,2 dead after p1 (A rows 0-63/128-191 read in p0,p1); units 4-7 (B) dead
// after p0. End-of-tile vmcnt(4) retires all of t+1, leaves t+2's 4 units.
template <int EPI>
__global__ __launch_bounds__(512, 2) void gemm256_bt_kernel(
    const ushort* __restrict__ A, const ushort* __restrict__ B,
    void* __restrict__ Cv, const float* __restrict__ scale,
    const float* __restrict__ oscale, int M, int N, int K) {
  constexpr int BK = 64;
  constexpr int TILEB = 256 * BK * 2;   // 32768 bytes per matrix tile
  constexpr int BUFB = 2 * TILEB;       // 65536 per buffer
  extern __shared__ char smem[];

  const int nbn = N >> 8;
  const int bid = blockIdx.x;
  const int cpx = gridDim.x >> 3;       // grid % 8 == 0
  const int swz = (bid & 7) * cpx + (bid >> 3);
  const int bm = swz / nbn, bn = swz % nbn;

  const int tid = threadIdx.x;
  const int lane = tid & 63;
  const int wv = tid >> 6;
  const int wm = wv >> 2, wn = wv & 3;  // 2 x 4 wave grid
  const int lr = lane & 15, lg = lane >> 4;

  const int srow = tid >> 3;                        // 0..63 within unit
  const int scol = ((tid & 7) ^ (srow & 7)) << 3;   // pre-swizzled src col
  const ushort* aS = A + (size_t)(bm * 256 + srow) * K + scol;
  const ushort* bS = B + (size_t)(bn * 256 + srow) * K + scol;
  const int ldsl = wv * 1024;

  auto STAGE = [&](int t, int u) {
    char* dst = smem + (t & 1) * BUFB + u * 8192 + ldsl;
    const ushort* src = (u < 4) ? aS + (size_t)(u * 64) * K + (size_t)t * BK
                                : bS + (size_t)((u - 4) * 64) * K + (size_t)t * BK;
    GLD16(src, dst);
  };

  const int nt = K >> 6;
  f32x4 acc[8][4] = {};

  // Prologue: tile0 full (8 units) + tile1 units 0,2,4,5; wait tile0 only.
#pragma unroll
  for (int u = 0; u < 8; ++u) STAGE(0, u);
  if (nt > 1) {
    STAGE(1, 0); STAGE(1, 2); STAGE(1, 4); STAGE(1, 5);
    asm volatile("s_waitcnt vmcnt(4)" ::: "memory");
  } else {
    asm volatile("s_waitcnt vmcnt(0)" ::: "memory");
  }
  __builtin_amdgcn_s_barrier();

  const int xorv = (lr & 7) << 4;
  const int k0 = (lg << 4) ^ xorv;          // ks0 byte offset within row
  const int k1 = (64 + (lg << 4)) ^ xorv;   // ks1
  const int abase = (wm * 128 + lr) * 128;
  const int bbase = TILEB + (wn * 64 + lr) * 128;

// One quadrant's 16 MFMAs: rows 2Q,2Q+1 x 4 cols x (ks0,ks1). Literal Q
// keeps acc indexing compile-time (no scratch).
#define MFMA_QUAD(Q)                                                         \
  __builtin_amdgcn_s_setprio(1);                                             \
  _Pragma("unroll") for (int fc = 0; fc < 4; ++fc)                           \
      acc[2*(Q)][fc] = __builtin_amdgcn_mfma_f32_16x16x32_bf16(              \
          aa0, b0[fc], acc[2*(Q)][fc], 0, 0, 0);                             \
  _Pragma("unroll") for (int fc = 0; fc < 4; ++fc)                           \
      acc[2*(Q)+1][fc] = __builtin_amdgcn_mfma_f32_16x16x32_bf16(            \
          aa2, b0[fc], acc[2*(Q)+1][fc], 0, 0, 0);                           \
  _Pragma("unroll") for (int fc = 0; fc < 4; ++fc)                           \
      acc[2*(Q)][fc] = __builtin_amdgcn_mfma_f32_16x16x32_bf16(              \
          aa1, b1[fc], acc[2*(Q)][fc], 0, 0, 0);                             \
  _Pragma("unroll") for (int fc = 0; fc < 4; ++fc)                           \
      acc[2*(Q)+1][fc] = __builtin_amdgcn_mfma_f32_16x16x32_bf16(            \
          aa3, b1[fc], acc[2*(Q)+1][fc], 0, 0, 0);                           \
  __builtin_amdgcn_s_setprio(0);

#define SYNC_IN()                                              \
  __builtin_amdgcn_s_barrier();                                \
  asm volatile("s_waitcnt lgkmcnt(0)" ::: "memory");           \
  __builtin_amdgcn_sched_barrier(0);

  for (int t = 0; t < nt; ++t) {
    const char* bufc = smem + (t & 1) * BUFB;
    const char* bA = bufc + abase;
    const char* bB = bufc + bbase;
    bf16x8 b0[4], b1[4];
    bf16x8 aa0, aa1, aa2, aa3;

    // ---- phase 0: quadrant 0 (frags 0,1) + all B reads ----
    aa0 = *(const bf16x8*)(bA + 0 * 2048 + k0);
    aa1 = *(const bf16x8*)(bA + 0 * 2048 + k1);
    aa2 = *(const bf16x8*)(bA + 1 * 2048 + k0);
    aa3 = *(const bf16x8*)(bA + 1 * 2048 + k1);
#pragma unroll
    for (int fc = 0; fc < 4; ++fc) {
      b0[fc] = *(const bf16x8*)(bB + fc * 2048 + k0);
      b1[fc] = *(const bf16x8*)(bB + fc * 2048 + k1);
    }
    if (t + 1 < nt) { STAGE(t + 1, 6); STAGE(t + 1, 7); }
    SYNC_IN();
    MFMA_QUAD(0);
    __builtin_amdgcn_s_barrier();

    // ---- phase 1: quadrant 1 (frags 2,3) ----
    aa0 = *(const bf16x8*)(bA + 2 * 2048 + k0);
    aa1 = *(const bf16x8*)(bA + 2 * 2048 + k1);
    aa2 = *(const bf16x8*)(bA + 3 * 2048 + k0);
    aa3 = *(const bf16x8*)(bA + 3 * 2048 + k1);
    if (t + 1 < nt) { STAGE(t + 1, 1); STAGE(t + 1, 3); }
    SYNC_IN();
    MFMA_QUAD(1);
    __builtin_amdgcn_s_barrier();

    // ---- phase 2: quadrant 2 (frags 4,5); stage (t+2)u0,u2 into cur buf ----
    aa0 = *(const bf16x8*)(bA + 4 * 2048 + k0);
    aa1 = *(const bf16x8*)(bA + 4 * 2048 + k1);
    aa2 = *(const bf16x8*)(bA + 5 * 2048 + k0);
    aa3 = *(const bf16x8*)(bA + 5 * 2048 + k1);
    asm volatile("" ::: "memory");  // keep stages below phase-1 barrier
    if (t + 2 < nt) { STAGE(t + 2, 0); STAGE(t + 2, 2); }
    SYNC_IN();
    MFMA_QUAD(2);
    __builtin_amdgcn_s_barrier();

    // ---- phase 3: quadrant 3 (frags 6,7); stage (t+2)u4,u5 ----
    aa0 = *(const bf16x8*)(bA + 6 * 2048 + k0);
    aa1 = *(const bf16x8*)(bA + 6 * 2048 + k1);
    aa2 = *(const bf16x8*)(bA + 7 * 2048 + k0);
    aa3 = *(const bf16x8*)(bA + 7 * 2048 + k1);
    asm volatile("" ::: "memory");
    if (t + 2 < nt) { STAGE(t + 2, 4); STAGE(t + 2, 5); }
    SYNC_IN();
    MFMA_QUAD(3);
    // End-of-tile wait: retire all of tile t+1, leave t+2's 4 units in flight.
    if (t + 2 < nt) {
      asm volatile("s_waitcnt vmcnt(4)" ::: "memory");
    } else if (t + 1 < nt) {
      asm volatile("s_waitcnt vmcnt(0)" ::: "memory");
    }
    __builtin_amdgcn_s_barrier();
  }
#undef MFMA_QUAD
#undef SYNC_IN

  // Epilogue. C/D layout: col = lane&15, row = (lane>>4)*4 + reg.
  if (EPI == 0) {
    ushort* C = (ushort*)Cv;
#pragma unroll
    for (int fc = 0; fc < 4; ++fc) {
      int gcol = bn * 256 + wn * 64 + fc * 16 + lr;
      float sc = scale[gcol];
#pragma unroll
      for (int fr = 0; fr < 8; ++fr) {
        int gr = bm * 256 + wm * 128 + fr * 16 + lg * 4;
#pragma unroll
        for (int r = 0; r < 4; ++r) {
          float v = acc[fr][fc][r] * sc;
          v = v > 0.f ? v : 0.f;
          C[(size_t)(gr + r) * N + gcol] = f2bf_rne(v);
        }
      }
    }
  } else {
    float* C = (float*)Cv;
    float osc = oscale[0];
#pragma unroll
    for (int fc = 0; fc < 4; ++fc) {
      int gcol = bn * 256 + wn * 64 + fc * 16 + lr;
      float sc = scale[gcol] * osc;
#pragma unroll
      for (int fr = 0; fr < 8; ++fr) {
        int gr = bm * 256 + wm * 128 + fr * 16 + lg * 4;
#pragma unroll
        for (int r = 0; r < 4; ++r) {
          C[(size_t)(gr + r) * N + gcol] = acc[fr][fc][r] * sc;
        }
      }
    }
  }
}

// ---------------- round-2 256x128 kernel (GEMM2, unchanged) ----------------
template <int EPI>
__global__ __launch_bounds__(512, 2) void gemm_bt_kernel(
    const ushort* __restrict__ A, const ushort* __restrict__ B,
    void* __restrict__ Cv, const float* __restrict__ scale,
    const float* __restrict__ oscale, int M, int N, int K) {
  constexpr int BM = 256, BN = 128, BK = 64;
  constexpr int ABYTES = BM * BK * 2;
  constexpr int BBYTES = BN * BK * 2;
  constexpr int BUFB = ABYTES + BBYTES;
  extern __shared__ char smem[];

  const int nbn = N / BN;
  const int nwg = gridDim.x;
  const int bid = blockIdx.x;
  const int cpx = nwg >> 3;
  const int swz = (bid & 7) * cpx + (bid >> 3);
  const int bm = swz / nbn, bn = swz % nbn;

  const int tid = threadIdx.x;
  const int lane = tid & 63;
  const int wv = tid >> 6;
  const int wm = wv >> 1, wn = wv & 1;
  const int lr = lane & 15, lg = lane >> 4;

  const int srow = tid >> 3;
  const int scol = ((tid & 7) ^ (srow & 7)) << 3;
  const ushort* aS = A + (size_t)(bm * BM + srow) * K + scol;
  const ushort* bS = B + (size_t)(bn * BN + srow) * K + scol;
  const int ldsl = wv * 1024;

  f32x4 acc[4][4] = {};
  const int nt = K / BK;

  auto STAGE = [&](int t, int q) {
    char* dA = smem + q * BUFB;
    char* dB = dA + ABYTES;
    const ushort* a0 = aS + (size_t)t * BK;
    const ushort* b0 = bS + (size_t)t * BK;
#pragma unroll
    for (int a = 0; a < 4; ++a)
      GLD16(a0 + (size_t)(a * 64) * K, dA + a * 8192 + ldsl);
#pragma unroll
    for (int b = 0; b < 2; ++b)
      GLD16(b0 + (size_t)(b * 64) * K, dB + b * 8192 + ldsl);
  };

  STAGE(0, 0);
  STAGE(1, 1);
  asm volatile("s_waitcnt vmcnt(6)" ::: "memory");
  __builtin_amdgcn_s_barrier();

  const int xorv = (lr & 7) << 4;
  int cur = 0;
  for (int t = 0; t < nt; ++t) {
    int nx = cur + 2; nx = (nx >= 3) ? nx - 3 : nx;
    if (t + 2 < nt) STAGE(t + 2, nx);

    const char* cA = smem + cur * BUFB;
    const char* cB = cA + ABYTES;
    bf16x8 af[2][4], bfr[2][4];
#pragma unroll
    for (int ks = 0; ks < 2; ++ks) {
      int ko = ((ks << 6) + (lg << 4)) ^ xorv;
#pragma unroll
      for (int i = 0; i < 4; ++i)
        af[ks][i] = *(const bf16x8*)(cA + ((wm * 64 + i * 16 + lr) << 7) + ko);
#pragma unroll
      for (int j = 0; j < 4; ++j)
        bfr[ks][j] = *(const bf16x8*)(cB + ((wn * 64 + j * 16 + lr) << 7) + ko);
    }

    __builtin_amdgcn_s_setprio(1);
#pragma unroll
    for (int ks = 0; ks < 2; ++ks)
#pragma unroll
      for (int i = 0; i < 4; ++i)
#pragma unroll
        for (int j = 0; j < 4; ++j)
          acc[i][j] = __builtin_amdgcn_mfma_f32_16x16x32_bf16(
              af[ks][i], bfr[ks][j], acc[i][j], 0, 0, 0);
    __builtin_amdgcn_s_setprio(0);

    if (t + 2 < nt) {
      asm volatile("s_waitcnt vmcnt(6)" ::: "memory");
    } else if (t + 1 < nt) {
      asm volatile("s_waitcnt vmcnt(0)" ::: "memory");
    }
    __builtin_amdgcn_s_barrier();
    cur = cur + 1; if (cur == 3) cur = 0;
  }

  if (EPI == 0) {
    ushort* C = (ushort*)Cv;
#pragma unroll
    for (int j = 0; j < 4; ++j) {
      int gcol = bn * BN + wn * 64 + j * 16 + lr;
      float sc = scale[gcol];
#pragma unroll
      for (int i = 0; i < 4; ++i) {
        int gr = bm * BM + wm * 64 + i * 16 + lg * 4;
#pragma unroll
        for (int r = 0; r < 4; ++r) {
          float v = acc[i][j][r] * sc;
          v = v > 0.f ? v : 0.f;
          C[(size_t)(gr + r) * N + gcol] = f2bf_rne(v);
        }
      }
    }
  } else {
    float* C = (float*)Cv;
    float osc = oscale[0];
#pragma unroll
    for (int j = 0; j < 4; ++j) {
      int gcol = bn * BN + wn * 64 + j * 16 + lr;
      float sc = scale[gcol] * osc;
#pragma unroll
      for (int i = 0; i < 4; ++i) {
        int gr = bm * BM + wm * 64 + i * 16 + lg * 4;
#pragma unroll
        for (int r = 0; r < 4; ++r) {
          C[(size_t)(gr + r) * N + gcol] = acc[i][j][r] * sc;
        }
      }
    }
  }
}

extern "C" void kernel_launch(void* const* d_in, const int* in_sizes, int n_in,
                              void* d_out, int out_size, void* d_ws,
                              size_t ws_size, hipStream_t stream) {
  const float* x   = (const float*)d_in[0];
  const float* upw = (const float*)d_in[1];
  const float* dnw = (const float*)d_in[2];
  const float* ups = (const float*)d_in[3];
  const float* dns = (const float*)d_in[4];
  const float* osc = (const float*)d_in[5];
  float* out = (float*)d_out;

  char* ws = (char*)d_ws;
  ushort* xb  = (ushort*)(ws);
  ushort* upb = (ushort*)(ws + 16777216);
  ushort* dnb = (ushort*)(ws + 16777216 + 33554432);
  ushort* hid = (ushort*)(ws + 16777216 + 33554432 + 33554432);

  cvt_bf16_kernel<<<2048, 256, 0, stream>>>(x, xb, (M_TOK * DM) / 4);
  sign_bf16_kernel<<<2048, 256, 0, stream>>>(upw, upb, (DH * DM) / 4);
  sign_bf16_kernel<<<2048, 256, 0, stream>>>(dnw, dnb, (DM * DH) / 4);

  const int smem1 = 2 * (256 * 64 * 2) * 2;                  // 131072
  const int smem2 = 3 * (256 * 64 * 2 + 128 * 64 * 2);       // 147456
  (void)hipFuncSetAttribute(reinterpret_cast<const void*>(gemm256_bt_kernel<0>),
                            hipFuncAttributeMaxDynamicSharedMemorySize, smem1);
  (void)hipFuncSetAttribute(reinterpret_cast<const void*>(gemm_bt_kernel<1>),
                            hipFuncAttributeMaxDynamicSharedMemorySize, smem2);

  // GEMM1: hidden[4096,8192] = xb @ upb^T, relu(*up_scale) -> bf16 (grid 512)
  gemm256_bt_kernel<0><<<(M_TOK / 256) * (DH / 256), 512, smem1, stream>>>(
      xb, upb, (void*)hid, ups, nullptr, M_TOK, DH, DM);
  // GEMM2: out[4096,2048] = hid @ dnb^T, *down_scale*out_scale -> f32 (grid 256)
  gemm_bt_kernel<1><<<(M_TOK / 256) * (DM / 128), 512, smem2, stream>>>(
      hid, dnb, (void*)out, dns, osc, M_TOK, DM, DH);
}

// Round 5
// 292.173 us; speedup vs baseline: 1.4650x; 1.0254x over previous
//
#include <hip/hip_runtime.h>
#include <stdint.h>

// TriXTile: out = (relu((x @ sign(up_w)^T) * up_scale) @ sign(down_w)^T) * down_scale * out_scale
// Round 5: GEMM1 rebuilt with 2-barriers-per-K-tile wave-skewed schedule:
// all 24 ds_reads issued up-front (4 fenced groups), progressive counted
// lgkmcnt interleaved with 4 MFMA quadrants, stages split early(other buf)/
// late(current buf after B1), counted vmcnt(4). GEMM2/prepass unchanged.

#define M_TOK 4096
#define DM 2048
#define DH 8192

typedef __attribute__((ext_vector_type(8))) short bf16x8;
typedef __attribute__((ext_vector_type(4))) float f32x4;

__device__ __forceinline__ ushort f2bf_rne(float f) {
  union { float f; uint32_t u; } c; c.f = f;
  uint32_t u = c.u;
  uint32_t r = (u + 0x7FFFu + ((u >> 16) & 1u)) >> 16;
  return (ushort)r;
}

__device__ __forceinline__ ushort signbf(float f) {
  union { float f; uint32_t u; } c; c.f = f;
  uint32_t mag = c.u & 0x7FFFFFFFu;
  return mag ? (ushort)(0x3F80u | ((c.u >> 16) & 0x8000u)) : (ushort)0;
}

#define GLD16(g, l)                                                     \
  __builtin_amdgcn_global_load_lds(                                     \
      (const __attribute__((address_space(1))) void*)(g),               \
      (__attribute__((address_space(3))) void*)(l), 16, 0, 0)

#define FENCE() asm volatile("" ::: "memory")

__global__ void cvt_bf16_kernel(const float* __restrict__ in,
                                ushort* __restrict__ out, int n4) {
  int stride = gridDim.x * blockDim.x;
  for (int i = blockIdx.x * blockDim.x + threadIdx.x; i < n4; i += stride) {
    float4 v = ((const float4*)in)[i];
    ushort4 o;
    o.x = f2bf_rne(v.x); o.y = f2bf_rne(v.y);
    o.z = f2bf_rne(v.z); o.w = f2bf_rne(v.w);
    ((ushort4*)out)[i] = o;
  }
}

__global__ void sign_bf16_kernel(const float* __restrict__ in,
                                 ushort* __restrict__ out, int n4) {
  int stride = gridDim.x * blockDim.x;
  for (int i = blockIdx.x * blockDim.x + threadIdx.x; i < n4; i += stride) {
    float4 v = ((const float4*)in)[i];
    ushort4 o;
    o.x = signbf(v.x); o.y = signbf(v.y);
    o.z = signbf(v.z); o.w = signbf(v.w);
    ((ushort4*)out)[i] = o;
  }
}

// ---------------- 256x256 2-barrier wave-skewed kernel (GEMM1) ----------------
// C = A[M,K] @ B[N,K]^T. 512 thr, 8 waves 2Mx4N, wave tile 128x64, BK=64.
// LDS: 2 buffers x 64KB. Units: u0-u3 = A rows u*64; u4-u7 = B rows (u-4)*64.
// Per wave, reads touch only A units {2wm,2wm+1} and B unit {4+wn}; all reads
// complete before B1 (lgkmcnt(0) precedes last MFMA group). Stage sets:
// EARLY E={6,7,1,3} for tile t+1 -> buffer (t+1)&1 (other; its reads finished
// at B1(t-1) < B2(t-1) which we passed). LATE L={0,2,4,5} for tile t+2 ->
// buffer t&1, issued after B1(t) (all waves' reads of it done).
// vmcnt ledger: entry 4 (L(t+1)) -> early +4 -> late +4 = 12; vmcnt(4)
// retires 8 oldest = exactly tile t+1; B2 publishes. Counted lgkm:
// groups g1=[aQ0(4)+B(8)], g2=[aQ1(4)], g3=[aQ2(4)], g4=[aQ3(4)], fenced;
// waits 4/4/4/0 between MFMA quadrants (DS retires in-order).
template <int EPI>
__global__ __launch_bounds__(512, 2) void gemm256_v5_kernel(
    const ushort* __restrict__ A, const ushort* __restrict__ B,
    void* __restrict__ Cv, const float* __restrict__ scale,
    const float* __restrict__ oscale, int M, int N, int K) {
  constexpr int BK = 64;
  constexpr int TILEB = 256 * BK * 2;   // 32768
  constexpr int BUFB = 2 * TILEB;       // 65536
  extern __shared__ char smem[];

  const int nbn = N >> 8;
  const int bid = blockIdx.x;
  const int cpx = gridDim.x >> 3;       // grid % 8 == 0
  const int swz = (bid & 7) * cpx + (bid >> 3);
  const int bm = swz / nbn, bn = swz % nbn;

  const int tid = threadIdx.x;
  const int lane = tid & 63;
  const int wv = tid >> 6;
  const int wm = wv >> 2, wn = wv & 3;  // 2 x 4 wave grid
  const int lr = lane & 15, lg = lane >> 4;

  const int srow = tid >> 3;
  const int scol = ((tid & 7) ^ (srow & 7)) << 3;   // pre-swizzled src col
  const ushort* aS = A + (size_t)(bm * 256 + srow) * K + scol;
  const ushort* bS = B + (size_t)(bn * 256 + srow) * K + scol;
  const int ldsl = wv * 1024;

  auto STAGE = [&](int t, int u) {
    char* dst = smem + (t & 1) * BUFB + u * 8192 + ldsl;
    const ushort* src = (u < 4) ? aS + (size_t)(u * 64) * K + (size_t)t * BK
                                : bS + (size_t)((u - 4) * 64) * K + (size_t)t * BK;
    GLD16(src, dst);
  };

  const int nt = K >> 6;
  f32x4 acc[8][4] = {};

  // Prologue: tile0 all 8 units + L(1); vmcnt(4) retires tile0, leaves L(1).
#pragma unroll
  for (int u = 0; u < 8; ++u) STAGE(0, u);
  if (nt > 1) {
    STAGE(1, 0); STAGE(1, 2); STAGE(1, 4); STAGE(1, 5);
    asm volatile("s_waitcnt vmcnt(4)" ::: "memory");
  } else {
    asm volatile("s_waitcnt vmcnt(0)" ::: "memory");
  }
  __builtin_amdgcn_s_barrier();

  const int xorv = (lr & 7) << 4;
  const int k0 = (lg << 4) ^ xorv;
  const int k1 = (64 + (lg << 4)) ^ xorv;
  const int abase = (wm * 128 + lr) * 128;
  const int bbase = TILEB + (wn * 64 + lr) * 128;

#define MFMA_G(Q, p, q, r, s)                                                \
  __builtin_amdgcn_s_setprio(1);                                             \
  _Pragma("unroll") for (int fc = 0; fc < 4; ++fc)                           \
      acc[2*(Q)][fc] = __builtin_amdgcn_mfma_f32_16x16x32_bf16(              \
          p, b0[fc], acc[2*(Q)][fc], 0, 0, 0);                               \
  _Pragma("unroll") for (int fc = 0; fc < 4; ++fc)                           \
      acc[2*(Q)+1][fc] = __builtin_amdgcn_mfma_f32_16x16x32_bf16(            \
          r, b0[fc], acc[2*(Q)+1][fc], 0, 0, 0);                             \
  _Pragma("unroll") for (int fc = 0; fc < 4; ++fc)                           \
      acc[2*(Q)][fc] = __builtin_amdgcn_mfma_f32_16x16x32_bf16(              \
          q, b1[fc], acc[2*(Q)][fc], 0, 0, 0);                               \
  _Pragma("unroll") for (int fc = 0; fc < 4; ++fc)                           \
      acc[2*(Q)+1][fc] = __builtin_amdgcn_mfma_f32_16x16x32_bf16(            \
          s, b1[fc], acc[2*(Q)+1][fc], 0, 0, 0);                             \
  __builtin_amdgcn_s_setprio(0);

#define WAITL(n)                                               \
  asm volatile("s_waitcnt lgkmcnt(" #n ")" ::: "memory");      \
  __builtin_amdgcn_sched_barrier(0);

  for (int t = 0; t < nt; ++t) {
    const char* bufc = smem + (t & 1) * BUFB;
    const char* bA = bufc + abase;
    const char* bB = bufc + bbase;
    bf16x8 b0[4], b1[4];
    bf16x8 p0, p1, p2, p3, q0, q1, q2, q3;

    // group 1: A frags 0,1 (bank P) + all B  [12 outstanding]
    p0 = *(const bf16x8*)(bA + 0 * 2048 + k0);
    p1 = *(const bf16x8*)(bA + 0 * 2048 + k1);
    p2 = *(const bf16x8*)(bA + 1 * 2048 + k0);
    p3 = *(const bf16x8*)(bA + 1 * 2048 + k1);
#pragma unroll
    for (int fc = 0; fc < 4; ++fc) {
      b0[fc] = *(const bf16x8*)(bB + fc * 2048 + k0);
      b1[fc] = *(const bf16x8*)(bB + fc * 2048 + k1);
    }
    FENCE();
    // group 2: A frags 2,3 (bank Q)  [16 outstanding]
    q0 = *(const bf16x8*)(bA + 2 * 2048 + k0);
    q1 = *(const bf16x8*)(bA + 2 * 2048 + k1);
    q2 = *(const bf16x8*)(bA + 3 * 2048 + k0);
    q3 = *(const bf16x8*)(bA + 3 * 2048 + k1);
    FENCE();
    // EARLY stages: tile t+1 units {6,7,1,3} -> other buffer (safe: its
    // reads finished before B2(t-1) which we passed).
    if (t + 1 < nt) { STAGE(t + 1, 6); STAGE(t + 1, 7);
                      STAGE(t + 1, 1); STAGE(t + 1, 3); }
    WAITL(4);            // g1 done (aQ0 + all B)
    MFMA_G(0, p0, p1, p2, p3);
    // group 3: A frags 4,5 -> bank P (WAR on p*: MFMAs latched operands)
    p0 = *(const bf16x8*)(bA + 4 * 2048 + k0);
    p1 = *(const bf16x8*)(bA + 4 * 2048 + k1);
    p2 = *(const bf16x8*)(bA + 5 * 2048 + k0);
    p3 = *(const bf16x8*)(bA + 5 * 2048 + k1);
    FENCE();
    WAITL(4);            // g2 done
    MFMA_G(1, q0, q1, q2, q3);
    // group 4: A frags 6,7 -> bank Q
    q0 = *(const bf16x8*)(bA + 6 * 2048 + k0);
    q1 = *(const bf16x8*)(bA + 6 * 2048 + k1);
    q2 = *(const bf16x8*)(bA + 7 * 2048 + k0);
    q3 = *(const bf16x8*)(bA + 7 * 2048 + k1);
    FENCE();
    WAITL(4);            // g3 done
    MFMA_G(2, p0, p1, p2, p3);
    WAITL(0);            // g4 done -> ALL reads of this buffer done
    MFMA_G(3, q0, q1, q2, q3);

    __builtin_amdgcn_s_barrier();   // B1: every wave finished reading buffer
    // LATE stages: tile t+2 units {0,2,4,5} -> current buffer (now dead).
    if (t + 2 < nt) { STAGE(t + 2, 0); STAGE(t + 2, 2);
                      STAGE(t + 2, 4); STAGE(t + 2, 5); }
    // Ledger: L(t+1)[4] + E(t+1)[4] + L(t+2)[4] = 12; retire tile t+1.
    if (t + 2 < nt) {
      asm volatile("s_waitcnt vmcnt(4)" ::: "memory");
    } else {
      asm volatile("s_waitcnt vmcnt(0)" ::: "memory");
    }
    __builtin_amdgcn_s_barrier();   // B2: tile t+1 published to all waves
  }
#undef MFMA_G
#undef WAITL

  // Epilogue. C/D layout: col = lane&15, row = (lane>>4)*4 + reg.
  if (EPI == 0) {
    ushort* C = (ushort*)Cv;
#pragma unroll
    for (int fc = 0; fc < 4; ++fc) {
      int gcol = bn * 256 + wn * 64 + fc * 16 + lr;
      float sc = scale[gcol];
#pragma unroll
      for (int fr = 0; fr < 8; ++fr) {
        int gr = bm * 256 + wm * 128 + fr * 16 + lg * 4;
#pragma unroll
        for (int r = 0; r < 4; ++r) {
          float v = acc[fr][fc][r] * sc;
          v = v > 0.f ? v : 0.f;
          C[(size_t)(gr + r) * N + gcol] = f2bf_rne(v);
        }
      }
    }
  } else {
    float* C = (float*)Cv;
    float osc = oscale[0];
#pragma unroll
    for (int fc = 0; fc < 4; ++fc) {
      int gcol = bn * 256 + wn * 64 + fc * 16 + lr;
      float sc = scale[gcol] * osc;
#pragma unroll
      for (int fr = 0; fr < 8; ++fr) {
        int gr = bm * 256 + wm * 128 + fr * 16 + lg * 4;
#pragma unroll
        for (int r = 0; r < 4; ++r) {
          C[(size_t)(gr + r) * N + gcol] = acc[fr][fc][r] * sc;
        }
      }
    }
  }
}

// ---------------- round-2 256x128 kernel (GEMM2, unchanged) ----------------
template <int EPI>
__global__ __launch_bounds__(512, 2) void gemm_bt_kernel(
    const ushort* __restrict__ A, const ushort* __restrict__ B,
    void* __restrict__ Cv, const float* __restrict__ scale,
    const float* __restrict__ oscale, int M, int N, int K) {
  constexpr int BM = 256, BN = 128, BK = 64;
  constexpr int ABYTES = BM * BK * 2;
  constexpr int BBYTES = BN * BK * 2;
  constexpr int BUFB = ABYTES + BBYTES;
  extern __shared__ char smem[];

  const int nbn = N / BN;
  const int nwg = gridDim.x;
  const int bid = blockIdx.x;
  const int cpx = nwg >> 3;
  const int swz = (bid & 7) * cpx + (bid >> 3);
  const int bm = swz / nbn, bn = swz % nbn;

  const int tid = threadIdx.x;
  const int lane = tid & 63;
  const int wv = tid >> 6;
  const int wm = wv >> 1, wn = wv & 1;
  const int lr = lane & 15, lg = lane >> 4;

  const int srow = tid >> 3;
  const int scol = ((tid & 7) ^ (srow & 7)) << 3;
  const ushort* aS = A + (size_t)(bm * BM + srow) * K + scol;
  const ushort* bS = B + (size_t)(bn * BN + srow) * K + scol;
  const int ldsl = wv * 1024;

  f32x4 acc[4][4] = {};
  const int nt = K / BK;

  auto STAGE = [&](int t, int q) {
    char* dA = smem + q * BUFB;
    char* dB = dA + ABYTES;
    const ushort* a0 = aS + (size_t)t * BK;
    const ushort* b0 = bS + (size_t)t * BK;
#pragma unroll
    for (int a = 0; a < 4; ++a)
      GLD16(a0 + (size_t)(a * 64) * K, dA + a * 8192 + ldsl);
#pragma unroll
    for (int b = 0; b < 2; ++b)
      GLD16(b0 + (size_t)(b * 64) * K, dB + b * 8192 + ldsl);
  };

  STAGE(0, 0);
  STAGE(1, 1);
  asm volatile("s_waitcnt vmcnt(6)" ::: "memory");
  __builtin_amdgcn_s_barrier();

  const int xorv = (lr & 7) << 4;
  int cur = 0;
  for (int t = 0; t < nt; ++t) {
    int nx = cur + 2; nx = (nx >= 3) ? nx - 3 : nx;
    if (t + 2 < nt) STAGE(t + 2, nx);

    const char* cA = smem + cur * BUFB;
    const char* cB = cA + ABYTES;
    bf16x8 af[2][4], bfr[2][4];
#pragma unroll
    for (int ks = 0; ks < 2; ++ks) {
      int ko = ((ks << 6) + (lg << 4)) ^ xorv;
#pragma unroll
      for (int i = 0; i < 4; ++i)
        af[ks][i] = *(const bf16x8*)(cA + ((wm * 64 + i * 16 + lr) << 7) + ko);
#pragma unroll
      for (int j = 0; j < 4; ++j)
        bfr[ks][j] = *(const bf16x8*)(cB + ((wn * 64 + j * 16 + lr) << 7) + ko);
    }

    __builtin_amdgcn_s_setprio(1);
#pragma unroll
    for (int ks = 0; ks < 2; ++ks)
#pragma unroll
      for (int i = 0; i < 4; ++i)
#pragma unroll
        for (int j = 0; j < 4; ++j)
          acc[i][j] = __builtin_amdgcn_mfma_f32_16x16x32_bf16(
              af[ks][i], bfr[ks][j], acc[i][j], 0, 0, 0);
    __builtin_amdgcn_s_setprio(0);

    if (t + 2 < nt) {
      asm volatile("s_waitcnt vmcnt(6)" ::: "memory");
    } else if (t + 1 < nt) {
      asm volatile("s_waitcnt vmcnt(0)" ::: "memory");
    }
    __builtin_amdgcn_s_barrier();
    cur = cur + 1; if (cur == 3) cur = 0;
  }

  if (EPI == 0) {
    ushort* C = (ushort*)Cv;
#pragma unroll
    for (int j = 0; j < 4; ++j) {
      int gcol = bn * BN + wn * 64 + j * 16 + lr;
      float sc = scale[gcol];
#pragma unroll
      for (int i = 0; i < 4; ++i) {
        int gr = bm * BM + wm * 64 + i * 16 + lg * 4;
#pragma unroll
        for (int r = 0; r < 4; ++r) {
          float v = acc[i][j][r] * sc;
          v = v > 0.f ? v : 0.f;
          C[(size_t)(gr + r) * N + gcol] = f2bf_rne(v);
        }
      }
    }
  } else {
    float* C = (float*)Cv;
    float osc = oscale[0];
#pragma unroll
    for (int j = 0; j < 4; ++j) {
      int gcol = bn * BN + wn * 64 + j * 16 + lr;
      float sc = scale[gcol] * osc;
#pragma unroll
      for (int i = 0; i < 4; ++i) {
        int gr = bm * BM + wm * 64 + i * 16 + lg * 4;
#pragma unroll
        for (int r = 0; r < 4; ++r) {
          C[(size_t)(gr + r) * N + gcol] = acc[i][j][r] * sc;
        }
      }
    }
  }
}

extern "C" void kernel_launch(void* const* d_in, const int* in_sizes, int n_in,
                              void* d_out, int out_size, void* d_ws,
                              size_t ws_size, hipStream_t stream) {
  const float* x   = (const float*)d_in[0];
  const float* upw = (const float*)d_in[1];
  const float* dnw = (const float*)d_in[2];
  const float* ups = (const float*)d_in[3];
  const float* dns = (const float*)d_in[4];
  const float* osc = (const float*)d_in[5];
  float* out = (float*)d_out;

  char* ws = (char*)d_ws;
  ushort* xb  = (ushort*)(ws);
  ushort* upb = (ushort*)(ws + 16777216);
  ushort* dnb = (ushort*)(ws + 16777216 + 33554432);
  ushort* hid = (ushort*)(ws + 16777216 + 33554432 + 33554432);

  cvt_bf16_kernel<<<2048, 256, 0, stream>>>(x, xb, (M_TOK * DM) / 4);
  sign_bf16_kernel<<<2048, 256, 0, stream>>>(upw, upb, (DH * DM) / 4);
  sign_bf16_kernel<<<2048, 256, 0, stream>>>(dnw, dnb, (DM * DH) / 4);

  const int smem1 = 2 * (256 * 64 * 2) * 2;                  // 131072
  const int smem2 = 3 * (256 * 64 * 2 + 128 * 64 * 2);       // 147456
  (void)hipFuncSetAttribute(reinterpret_cast<const void*>(gemm256_v5_kernel<0>),
                            hipFuncAttributeMaxDynamicSharedMemorySize, smem1);
  (void)hipFuncSetAttribute(reinterpret_cast<const void*>(gemm_bt_kernel<1>),
                            hipFuncAttributeMaxDynamicSharedMemorySize, smem2);

  // GEMM1: hidden[4096,8192] = xb @ upb^T, relu(*up_scale) -> bf16 (grid 512)
  gemm256_v5_kernel<0><<<(M_TOK / 256) * (DH / 256), 512, smem1, stream>>>(
      xb, upb, (void*)hid, ups, nullptr, M_TOK, DH, DM);
  // GEMM2: out[4096,2048] = hid @ dnb^T, *down_scale*out_scale -> f32 (grid 256)
  gemm_bt_kernel<1><<<(M_TOK / 256) * (DM / 128), 512, smem2, stream>>>(
      hid, dnb, (void*)out, dns, osc, M_TOK, DM, DH);
}

// Round 6
// 203.809 us; speedup vs baseline: 2.1002x; 1.4336x over previous
//
#include <hip/hip_runtime.h>
#include <stdint.h>

// TriXTile: out = (relu((x @ sign(up_w)^T) * up_scale) @ sign(down_w)^T) * down_scale * out_scale
// Round 6: int8 path. Ternary weights exact in i8; x/hidden per-row quantized.
// mfma_i32_16x16x64_i8 with BK=128 i8 is byte-identical geometry to BK=64 bf16
// -> same staging/swizzle/vmcnt structure, half the K-tiles, half the bytes.

#define M_TOK 4096
#define DM 2048
#define DH 8192

typedef __attribute__((ext_vector_type(4))) int i32x4;
typedef __attribute__((ext_vector_type(4))) float f32x4;
typedef __attribute__((ext_vector_type(8))) unsigned short u16x8;

__device__ __forceinline__ ushort f2bf_rne(float f) {
  union { float f; uint32_t u; } c; c.f = f;
  uint32_t u = c.u;
  uint32_t r = (u + 0x7FFFu + ((u >> 16) & 1u)) >> 16;
  return (ushort)r;
}

__device__ __forceinline__ float bf2f(ushort u) {
  union { uint32_t u; float f; } c; c.u = (uint32_t)u << 16;
  return c.f;
}

#define GLD16(g, l)                                                     \
  __builtin_amdgcn_global_load_lds(                                     \
      (const __attribute__((address_space(1))) void*)(g),               \
      (__attribute__((address_space(3))) void*)(l), 16, 0, 0)

#define FENCE() asm volatile("" ::: "memory")

// ---- quantize x: one block per row; row absmax -> sx[row]; i8 out ----
__global__ __launch_bounds__(256) void quantx_kernel(
    const float* __restrict__ x, int8_t* __restrict__ xq,
    float* __restrict__ sx) {
  const int row = blockIdx.x, tid = threadIdx.x;
  const float4* xr = (const float4*)(x + (size_t)row * 2048);
  float4 a = xr[tid * 2], b = xr[tid * 2 + 1];
  float m = fmaxf(fmaxf(fmaxf(fabsf(a.x), fabsf(a.y)), fmaxf(fabsf(a.z), fabsf(a.w))),
                  fmaxf(fmaxf(fabsf(b.x), fabsf(b.y)), fmaxf(fabsf(b.z), fabsf(b.w))));
#pragma unroll
  for (int off = 32; off >= 1; off >>= 1) m = fmaxf(m, __shfl_xor(m, off));
  __shared__ float red[4];
  if ((tid & 63) == 0) red[tid >> 6] = m;
  __syncthreads();
  m = fmaxf(fmaxf(red[0], red[1]), fmaxf(red[2], red[3]));
  const float inv = m > 0.f ? 127.f / m : 0.f;
  if (tid == 0) sx[row] = m > 0.f ? m / 127.f : 0.f;
  auto q8 = [&](float v) -> uint32_t {
    float q = rintf(v * inv);
    q = fminf(fmaxf(q, -127.f), 127.f);
    return (uint32_t)(uint8_t)(int8_t)(int)q;
  };
  uint32_t w0 = q8(a.x) | (q8(a.y) << 8) | (q8(a.z) << 16) | (q8(a.w) << 24);
  uint32_t w1 = q8(b.x) | (q8(b.y) << 8) | (q8(b.z) << 16) | (q8(b.w) << 24);
  uint32_t* o = (uint32_t*)(xq + (size_t)row * 2048);
  o[tid * 2] = w0;
  o[tid * 2 + 1] = w1;
}

// ---- sign(w) -> i8 {-1,0,1} ----
__global__ void signq_kernel(const float* __restrict__ in,
                             int8_t* __restrict__ out, int n4) {
  int stride = gridDim.x * blockDim.x;
  auto s8 = [](float v) -> uint32_t {
    int s = (v > 0.f) - (v < 0.f);
    return (uint32_t)(uint8_t)(int8_t)s;
  };
  for (int i = blockIdx.x * blockDim.x + threadIdx.x; i < n4; i += stride) {
    float4 v = ((const float4*)in)[i];
    ((uint32_t*)out)[i] = s8(v.x) | (s8(v.y) << 8) | (s8(v.z) << 16) | (s8(v.w) << 24);
  }
}

// ---- quantize hidden (bf16, post-relu >=0): row absmax -> sh[row]; i8 ----
__global__ __launch_bounds__(256) void quanth_kernel(
    const ushort* __restrict__ hid, int8_t* __restrict__ hq,
    float* __restrict__ sh) {
  const int row = blockIdx.x, tid = threadIdx.x;
  const u16x8* hr = (const u16x8*)(hid + (size_t)row * 8192);
  u16x8 h[4];
  float m = 0.f;
#pragma unroll
  for (int s = 0; s < 4; ++s) {
    h[s] = hr[tid * 4 + s];
#pragma unroll
    for (int j = 0; j < 8; ++j) m = fmaxf(m, fabsf(bf2f(h[s][j])));
  }
#pragma unroll
  for (int off = 32; off >= 1; off >>= 1) m = fmaxf(m, __shfl_xor(m, off));
  __shared__ float red[4];
  if ((tid & 63) == 0) red[tid >> 6] = m;
  __syncthreads();
  m = fmaxf(fmaxf(red[0], red[1]), fmaxf(red[2], red[3]));
  const float inv = m > 0.f ? 127.f / m : 0.f;
  if (tid == 0) sh[row] = m > 0.f ? m / 127.f : 0.f;
  auto q8 = [&](float v) -> uint32_t {
    float q = rintf(v * inv);
    q = fminf(fmaxf(q, -127.f), 127.f);
    return (uint32_t)(uint8_t)(int8_t)(int)q;
  };
  uint32_t* o = (uint32_t*)(hq + (size_t)row * 8192);
#pragma unroll
  for (int s = 0; s < 4; ++s) {
    uint32_t w0 = q8(bf2f(h[s][0])) | (q8(bf2f(h[s][1])) << 8) |
                  (q8(bf2f(h[s][2])) << 16) | (q8(bf2f(h[s][3])) << 24);
    uint32_t w1 = q8(bf2f(h[s][4])) | (q8(bf2f(h[s][5])) << 8) |
                  (q8(bf2f(h[s][6])) << 16) | (q8(bf2f(h[s][7])) << 24);
    o[tid * 8 + s * 2] = w0;
    o[tid * 8 + s * 2 + 1] = w1;
  }
}

// ---------------- GEMM1: 256x256 i8, v5 2-barrier schedule ----------------
// hid[M,N] = relu((xq @ upq^T) * sx[row] * ups[col]) -> bf16. K bytes = 2048.
// BK=128 i8 (128B rows) == byte geometry of BK=64 bf16. nt = 16.
__global__ __launch_bounds__(512, 2) void gemm1_i8_kernel(
    const int8_t* __restrict__ A, const int8_t* __restrict__ B,
    ushort* __restrict__ C, const float* __restrict__ sx,
    const float* __restrict__ ups, int M, int N, int K) {
  constexpr int TILEB = 256 * 128;      // 32768
  constexpr int BUFB = 2 * TILEB;       // 65536
  extern __shared__ char smem[];

  const int nbn = N >> 8;
  const int bid = blockIdx.x;
  const int cpx = gridDim.x >> 3;
  const int swz = (bid & 7) * cpx + (bid >> 3);
  const int bm = swz / nbn, bn = swz % nbn;

  const int tid = threadIdx.x;
  const int lane = tid & 63;
  const int wv = tid >> 6;
  const int wm = wv >> 2, wn = wv & 3;  // 2 x 4 waves, 128x64 each
  const int lr = lane & 15, lg = lane >> 4;

  const int srow = tid >> 3;
  const int scolB = ((tid & 7) ^ (srow & 7)) << 4;   // byte offset, pre-swizzled
  const int8_t* aS = A + (size_t)(bm * 256 + srow) * K + scolB;
  const int8_t* bS = B + (size_t)(bn * 256 + srow) * K + scolB;
  const int ldsl = wv * 1024;

  auto STAGE = [&](int t, int u) {
    char* dst = smem + (t & 1) * BUFB + u * 8192 + ldsl;
    const int8_t* src = (u < 4) ? aS + (size_t)(u * 64) * K + (size_t)t * 128
                                : bS + (size_t)((u - 4) * 64) * K + (size_t)t * 128;
    GLD16(src, dst);
  };

  const int nt = K >> 7;
  i32x4 acc[8][4] = {};

#pragma unroll
  for (int u = 0; u < 8; ++u) STAGE(0, u);
  if (nt > 1) {
    STAGE(1, 0); STAGE(1, 2); STAGE(1, 4); STAGE(1, 5);
    asm volatile("s_waitcnt vmcnt(4)" ::: "memory");
  } else {
    asm volatile("s_waitcnt vmcnt(0)" ::: "memory");
  }
  __builtin_amdgcn_s_barrier();

  const int xorv = (lr & 7) << 4;
  const int k0 = (lg << 4) ^ xorv;
  const int k1 = (64 + (lg << 4)) ^ xorv;
  const int abase = (wm * 128 + lr) * 128;
  const int bbase = TILEB + (wn * 64 + lr) * 128;

#define MFMA_G(Q, p, q, r, s)                                                \
  __builtin_amdgcn_s_setprio(1);                                             \
  _Pragma("unroll") for (int fc = 0; fc < 4; ++fc)                           \
      acc[2*(Q)][fc] = __builtin_amdgcn_mfma_i32_16x16x64_i8(                \
          p, b0[fc], acc[2*(Q)][fc], 0, 0, 0);                               \
  _Pragma("unroll") for (int fc = 0; fc < 4; ++fc)                           \
      acc[2*(Q)+1][fc] = __builtin_amdgcn_mfma_i32_16x16x64_i8(              \
          r, b0[fc], acc[2*(Q)+1][fc], 0, 0, 0);                             \
  _Pragma("unroll") for (int fc = 0; fc < 4; ++fc)                           \
      acc[2*(Q)][fc] = __builtin_amdgcn_mfma_i32_16x16x64_i8(                \
          q, b1[fc], acc[2*(Q)][fc], 0, 0, 0);                               \
  _Pragma("unroll") for (int fc = 0; fc < 4; ++fc)                           \
      acc[2*(Q)+1][fc] = __builtin_amdgcn_mfma_i32_16x16x64_i8(              \
          s, b1[fc], acc[2*(Q)+1][fc], 0, 0, 0);                             \
  __builtin_amdgcn_s_setprio(0);

#define WAITL(n)                                               \
  asm volatile("s_waitcnt lgkmcnt(" #n ")" ::: "memory");      \
  __builtin_amdgcn_sched_barrier(0);

  for (int t = 0; t < nt; ++t) {
    const char* bufc = smem + (t & 1) * BUFB;
    const char* bA = bufc + abase;
    const char* bB = bufc + bbase;
    i32x4 b0[4], b1[4];
    i32x4 p0, p1, p2, p3, q0, q1, q2, q3;

    p0 = *(const i32x4*)(bA + 0 * 2048 + k0);
    p1 = *(const i32x4*)(bA + 0 * 2048 + k1);
    p2 = *(const i32x4*)(bA + 1 * 2048 + k0);
    p3 = *(const i32x4*)(bA + 1 * 2048 + k1);
#pragma unroll
    for (int fc = 0; fc < 4; ++fc) {
      b0[fc] = *(const i32x4*)(bB + fc * 2048 + k0);
      b1[fc] = *(const i32x4*)(bB + fc * 2048 + k1);
    }
    FENCE();
    q0 = *(const i32x4*)(bA + 2 * 2048 + k0);
    q1 = *(const i32x4*)(bA + 2 * 2048 + k1);
    q2 = *(const i32x4*)(bA + 3 * 2048 + k0);
    q3 = *(const i32x4*)(bA + 3 * 2048 + k1);
    FENCE();
    if (t + 1 < nt) { STAGE(t + 1, 6); STAGE(t + 1, 7);
                      STAGE(t + 1, 1); STAGE(t + 1, 3); }
    WAITL(4);
    MFMA_G(0, p0, p1, p2, p3);
    p0 = *(const i32x4*)(bA + 4 * 2048 + k0);
    p1 = *(const i32x4*)(bA + 4 * 2048 + k1);
    p2 = *(const i32x4*)(bA + 5 * 2048 + k0);
    p3 = *(const i32x4*)(bA + 5 * 2048 + k1);
    FENCE();
    WAITL(4);
    MFMA_G(1, q0, q1, q2, q3);
    q0 = *(const i32x4*)(bA + 6 * 2048 + k0);
    q1 = *(const i32x4*)(bA + 6 * 2048 + k1);
    q2 = *(const i32x4*)(bA + 7 * 2048 + k0);
    q3 = *(const i32x4*)(bA + 7 * 2048 + k1);
    FENCE();
    WAITL(4);
    MFMA_G(2, p0, p1, p2, p3);
    WAITL(0);
    MFMA_G(3, q0, q1, q2, q3);

    __builtin_amdgcn_s_barrier();   // B1: all reads of current buffer done
    if (t + 2 < nt) { STAGE(t + 2, 0); STAGE(t + 2, 2);
                      STAGE(t + 2, 4); STAGE(t + 2, 5); }
    if (t + 2 < nt) {
      asm volatile("s_waitcnt vmcnt(4)" ::: "memory");
    } else {
      asm volatile("s_waitcnt vmcnt(0)" ::: "memory");
    }
    __builtin_amdgcn_s_barrier();   // B2: tile t+1 published
  }
#undef MFMA_G
#undef WAITL

  // Epilogue: v = relu(acc * sx[row] * ups[col]) -> bf16
  float uc[4];
#pragma unroll
  for (int fc = 0; fc < 4; ++fc) uc[fc] = ups[bn * 256 + wn * 64 + fc * 16 + lr];
#pragma unroll
  for (int fr = 0; fr < 8; ++fr) {
    int gr = bm * 256 + wm * 128 + fr * 16 + lg * 4;
    float4 sxv = *(const float4*)(sx + gr);
#pragma unroll
    for (int fc = 0; fc < 4; ++fc) {
      int gcol = bn * 256 + wn * 64 + fc * 16 + lr;
      float s0 = sxv.x, s1 = sxv.y, s2 = sxv.z, s3 = sxv.w;
      float v0 = (float)acc[fr][fc][0] * s0 * uc[fc];
      float v1 = (float)acc[fr][fc][1] * s1 * uc[fc];
      float v2 = (float)acc[fr][fc][2] * s2 * uc[fc];
      float v3 = (float)acc[fr][fc][3] * s3 * uc[fc];
      C[(size_t)(gr + 0) * N + gcol] = f2bf_rne(v0 > 0.f ? v0 : 0.f);
      C[(size_t)(gr + 1) * N + gcol] = f2bf_rne(v1 > 0.f ? v1 : 0.f);
      C[(size_t)(gr + 2) * N + gcol] = f2bf_rne(v2 > 0.f ? v2 : 0.f);
      C[(size_t)(gr + 3) * N + gcol] = f2bf_rne(v3 > 0.f ? v3 : 0.f);
    }
  }
}

// ---------------- GEMM2: 256x128 i8, round-2 3-buffer schedule ----------------
// out[M,N] = (hq @ dnq^T) * sh[row] * dns[col] * osc -> f32. K bytes = 8192, nt=64.
__global__ __launch_bounds__(512, 2) void gemm2_i8_kernel(
    const int8_t* __restrict__ A, const int8_t* __restrict__ B,
    float* __restrict__ C, const float* __restrict__ sh,
    const float* __restrict__ dns, const float* __restrict__ oscale,
    int M, int N, int K) {
  constexpr int ABYTES = 256 * 128;     // 32768
  constexpr int BBYTES = 128 * 128;     // 16384
  constexpr int BUFB = ABYTES + BBYTES; // 49152
  extern __shared__ char smem[];

  const int nbn = N >> 7;
  const int bid = blockIdx.x;
  const int cpx = gridDim.x >> 3;
  const int swz = (bid & 7) * cpx + (bid >> 3);
  const int bm = swz / nbn, bn = swz % nbn;

  const int tid = threadIdx.x;
  const int lane = tid & 63;
  const int wv = tid >> 6;
  const int wm = wv >> 1, wn = wv & 1;  // 4 x 2 waves, 64x64 each
  const int lr = lane & 15, lg = lane >> 4;

  const int srow = tid >> 3;
  const int scolB = ((tid & 7) ^ (srow & 7)) << 4;
  const int8_t* aS = A + (size_t)(bm * 256 + srow) * K + scolB;
  const int8_t* bS = B + (size_t)(bn * 128 + srow) * K + scolB;
  const int ldsl = wv * 1024;

  i32x4 acc[4][4] = {};
  const int nt = K >> 7;

  auto STAGE = [&](int t, int q) {
    char* dA = smem + q * BUFB;
    char* dB = dA + ABYTES;
    const int8_t* a0 = aS + (size_t)t * 128;
    const int8_t* b0 = bS + (size_t)t * 128;
#pragma unroll
    for (int a = 0; a < 4; ++a)
      GLD16(a0 + (size_t)(a * 64) * K, dA + a * 8192 + ldsl);
#pragma unroll
    for (int b = 0; b < 2; ++b)
      GLD16(b0 + (size_t)(b * 64) * K, dB + b * 8192 + ldsl);
  };

  STAGE(0, 0);
  STAGE(1, 1);
  asm volatile("s_waitcnt vmcnt(6)" ::: "memory");
  __builtin_amdgcn_s_barrier();

  const int xorv = (lr & 7) << 4;
  int cur = 0;
  for (int t = 0; t < nt; ++t) {
    int nx = cur + 2; nx = (nx >= 3) ? nx - 3 : nx;
    if (t + 2 < nt) STAGE(t + 2, nx);

    const char* cA = smem + cur * BUFB;
    const char* cB = cA + ABYTES;
    i32x4 af[2][4], bfr[2][4];
#pragma unroll
    for (int ks = 0; ks < 2; ++ks) {
      int ko = ((ks << 6) + (lg << 4)) ^ xorv;
#pragma unroll
      for (int i = 0; i < 4; ++i)
        af[ks][i] = *(const i32x4*)(cA + ((wm * 64 + i * 16 + lr) << 7) + ko);
#pragma unroll
      for (int j = 0; j < 4; ++j)
        bfr[ks][j] = *(const i32x4*)(cB + ((wn * 64 + j * 16 + lr) << 7) + ko);
    }

    __builtin_amdgcn_s_setprio(1);
#pragma unroll
    for (int ks = 0; ks < 2; ++ks)
#pragma unroll
      for (int i = 0; i < 4; ++i)
#pragma unroll
        for (int j = 0; j < 4; ++j)
          acc[i][j] = __builtin_amdgcn_mfma_i32_16x16x64_i8(
              af[ks][i], bfr[ks][j], acc[i][j], 0, 0, 0);
    __builtin_amdgcn_s_setprio(0);

    if (t + 2 < nt) {
      asm volatile("s_waitcnt vmcnt(6)" ::: "memory");
    } else if (t + 1 < nt) {
      asm volatile("s_waitcnt vmcnt(0)" ::: "memory");
    }
    __builtin_amdgcn_s_barrier();
    cur = cur + 1; if (cur == 3) cur = 0;
  }

  // Epilogue: out = acc * sh[row] * dns[col] * osc -> f32
  float osc_v = oscale[0];
  float dc[4];
#pragma unroll
  for (int j = 0; j < 4; ++j)
    dc[j] = dns[bn * 128 + wn * 64 + j * 16 + lr] * osc_v;
#pragma unroll
  for (int i = 0; i < 4; ++i) {
    int gr = bm * 256 + wm * 64 + i * 16 + lg * 4;
    float4 shv = *(const float4*)(sh + gr);
#pragma unroll
    for (int j = 0; j < 4; ++j) {
      int gcol = bn * 128 + wn * 64 + j * 16 + lr;
      C[(size_t)(gr + 0) * N + gcol] = (float)acc[i][j][0] * shv.x * dc[j];
      C[(size_t)(gr + 1) * N + gcol] = (float)acc[i][j][1] * shv.y * dc[j];
      C[(size_t)(gr + 2) * N + gcol] = (float)acc[i][j][2] * shv.z * dc[j];
      C[(size_t)(gr + 3) * N + gcol] = (float)acc[i][j][3] * shv.w * dc[j];
    }
  }
}

extern "C" void kernel_launch(void* const* d_in, const int* in_sizes, int n_in,
                              void* d_out, int out_size, void* d_ws,
                              size_t ws_size, hipStream_t stream) {
  const float* x   = (const float*)d_in[0];
  const float* upw = (const float*)d_in[1];
  const float* dnw = (const float*)d_in[2];
  const float* ups = (const float*)d_in[3];
  const float* dns = (const float*)d_in[4];
  const float* osc = (const float*)d_in[5];
  float* out = (float*)d_out;

  char* ws = (char*)d_ws;
  int8_t* xq  = (int8_t*)(ws);                      //  8 MB [4096][2048]
  int8_t* upq = (int8_t*)(ws + 8388608);            // 16 MB [8192][2048]
  int8_t* dnq = (int8_t*)(ws + 25165824);           // 16 MB [2048][8192]
  ushort* hid = (ushort*)(ws + 41943040);           // 64 MB [4096][8192] bf16
  int8_t* hq  = (int8_t*)(ws + 109051904);          // 32 MB [4096][8192]
  float*  sx  = (float*)(ws + 142606336);           // 16 KB [4096]
  float*  sh  = (float*)(ws + 142622720);           // 16 KB [4096]

  quantx_kernel<<<M_TOK, 256, 0, stream>>>(x, xq, sx);
  signq_kernel<<<2048, 256, 0, stream>>>(upw, upq, (DH * DM) / 4);
  signq_kernel<<<2048, 256, 0, stream>>>(dnw, dnq, (DM * DH) / 4);

  const int smem1 = 131072;
  const int smem2 = 147456;
  (void)hipFuncSetAttribute(reinterpret_cast<const void*>(gemm1_i8_kernel),
                            hipFuncAttributeMaxDynamicSharedMemorySize, smem1);
  (void)hipFuncSetAttribute(reinterpret_cast<const void*>(gemm2_i8_kernel),
                            hipFuncAttributeMaxDynamicSharedMemorySize, smem2);

  // GEMM1: hid = relu((xq @ upq^T) * sx * ups) -> bf16  (grid 512)
  gemm1_i8_kernel<<<(M_TOK / 256) * (DH / 256), 512, smem1, stream>>>(
      xq, upq, hid, sx, ups, M_TOK, DH, DM);
  // quantize hidden per-row -> i8 + sh
  quanth_kernel<<<M_TOK, 256, 0, stream>>>(hid, hq, sh);
  // GEMM2: out = (hq @ dnq^T) * sh * dns * osc -> f32  (grid 256)
  gemm2_i8_kernel<<<(M_TOK / 256) * (DM / 128), 512, smem2, stream>>>(
      hq, dnq, out, sh, dns, osc, M_TOK, DM, DH);
}